// Round 1
// baseline (844.813 us; speedup 1.0000x reference)
//
#include <hip/hip_runtime.h>
#include <cstdint>
#include <cstddef>

#define DD 128
#define EPSV 1e-5f

// ---------------------------------------------------------------- utilities

__global__ void zero_int_kernel(int* __restrict__ p, int n) {
  int i = blockIdx.x * blockDim.x + threadIdx.x;
  if (i < n) p[i] = 0;
}

__global__ void degree_kernel(const int* __restrict__ dst, int* __restrict__ deg, int E) {
  int e = blockIdx.x * blockDim.x + threadIdx.x;
  if (e < E) atomicAdd(&deg[dst[e]], 1);
}

// Exclusive scan of deg -> row_start/cursor, plus inv_deg. Single 1024-thread block,
// wave-shuffle scans (few barriers). 49 chunks for N=50000 -> a few microseconds.
__global__ __launch_bounds__(1024) void scan_kernel(const int* __restrict__ deg,
                                                    int* __restrict__ row_start,
                                                    int* __restrict__ cursor,
                                                    float* __restrict__ inv_deg, int n) {
  __shared__ int wsum[16];
  __shared__ int wpref[16];
  __shared__ int s_running;
  __shared__ int s_total;
  int t = threadIdx.x;
  int lane = t & 63, wid = t >> 6;
  if (t == 0) s_running = 0;
  __syncthreads();
  for (int base = 0; base < n; base += 1024) {
    int i = base + t;
    int v = (i < n) ? deg[i] : 0;
    int sc = v;
#pragma unroll
    for (int off = 1; off < 64; off <<= 1) {
      int u = __shfl_up(sc, off, 64);
      if (lane >= off) sc += u;
    }
    if (lane == 63) wsum[wid] = sc;
    __syncthreads();
    if (t == 0) {
      int a = 0;
#pragma unroll
      for (int w = 0; w < 16; ++w) { wpref[w] = a; a += wsum[w]; }
      s_total = a;
    }
    __syncthreads();
    int run = s_running;
    int excl = run + wpref[wid] + (sc - v);
    if (i < n) {
      row_start[i] = excl;
      cursor[i] = excl;
      inv_deg[i] = 1.0f / fmaxf((float)v, 1.0f);
    }
    __syncthreads();
    if (t == 0) s_running = run + s_total;
    __syncthreads();
  }
  if (t == 0) row_start[n] = s_running;
}

__global__ void fill_kernel(const int* __restrict__ src, const int* __restrict__ dst,
                            int* cursor, int* __restrict__ col, int E) {
  int e = blockIdx.x * blockDim.x + threadIdx.x;
  if (e < E) {
    int d = dst[e];
    int p = atomicAdd(&cursor[d], 1);
    col[p] = src[e];
  }
}

// ------------------------------------------------------------- aggregation
// One wave per node; lane covers 2 feature columns (64*2 = 128). Each neighbor
// row is one coalesced 512B wave read. No atomics.
__global__ __launch_bounds__(256) void agg_kernel(const float* __restrict__ h, int ldh,
                                                  const int* __restrict__ row_start,
                                                  const int* __restrict__ col,
                                                  const float* __restrict__ inv_deg,
                                                  float* __restrict__ agg, int n) {
  int wib = threadIdx.x >> 6;
  int lane = threadIdx.x & 63;
  int node = blockIdx.x * (blockDim.x >> 6) + wib;
  if (node >= n) return;
  int beg = row_start[node];
  int end = row_start[node + 1];
  int c = lane * 2;
  float ax = 0.f, ay = 0.f;
  for (int j = beg; j < end; ++j) {
    int s = col[j];
    const float2 v = *reinterpret_cast<const float2*>(h + (size_t)s * ldh + c);
    ax += v.x;
    ay += v.y;
  }
  float w = inv_deg[node];
  float2 o;
  o.x = ax * w;
  o.y = ay * w;
  *reinterpret_cast<float2*>(agg + (size_t)node * DD + c) = o;
}

// ------------------------------------------------- fused layer GEMM + BN + ReLU
// out[n,c] = relu(BN(agg[n,:]@Wl[:,c] + bl[c] + h[n,:]@Wr[:,c]))
// Tile: 64 rows x 128 cols, K=128 (whole reduction, single LDS stage).
// 256 threads: thread = 8 rows x 4 cols. W rows streamed from L2.
__global__ __launch_bounds__(256) void layer_gemm(
    const float* __restrict__ hin, int ldh, const float* __restrict__ agg,
    const float* __restrict__ Wl, const float* __restrict__ bl,
    const float* __restrict__ Wr, const float* __restrict__ gamma,
    const float* __restrict__ beta, const float* __restrict__ rmean,
    const float* __restrict__ rvar, float* __restrict__ out, int ldo, int n) {
  __shared__ float sA[64][DD];
  __shared__ float sH[64][DD];
  int t = threadIdx.x;
  int row0 = blockIdx.x * 64;
#pragma unroll
  for (int it = 0; it < 8; ++it) {
    int idx = it * 256 + t;
    int r = idx >> 5;
    int c4 = (idx & 31) * 4;
    int gr = row0 + r;
    float4 va = {0.f, 0.f, 0.f, 0.f};
    float4 vh = {0.f, 0.f, 0.f, 0.f};
    if (gr < n) {
      va = *reinterpret_cast<const float4*>(agg + (size_t)gr * DD + c4);
      vh = *reinterpret_cast<const float4*>(hin + (size_t)gr * ldh + c4);
    }
    *reinterpret_cast<float4*>(&sA[r][c4]) = va;
    *reinterpret_cast<float4*>(&sH[r][c4]) = vh;
  }
  __syncthreads();

  int tx = t & 31, ty = t >> 5;
  int c0 = tx * 4, r0 = ty * 8;
  float acc[8][4];
#pragma unroll
  for (int i = 0; i < 8; ++i) acc[i][0] = acc[i][1] = acc[i][2] = acc[i][3] = 0.f;

  for (int k = 0; k < DD; ++k) {
    float4 wl = *reinterpret_cast<const float4*>(Wl + (size_t)k * DD + c0);
    float4 wr = *reinterpret_cast<const float4*>(Wr + (size_t)k * DD + c0);
#pragma unroll
    for (int i = 0; i < 8; ++i) {
      float a = sA[r0 + i][k];
      float h = sH[r0 + i][k];
      acc[i][0] = fmaf(a, wl.x, fmaf(h, wr.x, acc[i][0]));
      acc[i][1] = fmaf(a, wl.y, fmaf(h, wr.y, acc[i][1]));
      acc[i][2] = fmaf(a, wl.z, fmaf(h, wr.z, acc[i][2]));
      acc[i][3] = fmaf(a, wl.w, fmaf(h, wr.w, acc[i][3]));
    }
  }

  float4 blv = *reinterpret_cast<const float4*>(bl + c0);
  float4 gm = *reinterpret_cast<const float4*>(gamma + c0);
  float4 bt = *reinterpret_cast<const float4*>(beta + c0);
  float4 rm = *reinterpret_cast<const float4*>(rmean + c0);
  float4 rv = *reinterpret_cast<const float4*>(rvar + c0);
  float scx = gm.x * rsqrtf(rv.x + EPSV);
  float scy = gm.y * rsqrtf(rv.y + EPSV);
  float scz = gm.z * rsqrtf(rv.z + EPSV);
  float scw = gm.w * rsqrtf(rv.w + EPSV);
  float shx = (blv.x - rm.x) * scx + bt.x;
  float shy = (blv.y - rm.y) * scy + bt.y;
  float shz = (blv.z - rm.z) * scz + bt.z;
  float shw = (blv.w - rm.w) * scw + bt.w;

#pragma unroll
  for (int i = 0; i < 8; ++i) {
    int gr = row0 + r0 + i;
    if (gr < n) {
      float4 o;
      o.x = fmaxf(fmaf(acc[i][0], scx, shx), 0.f);
      o.y = fmaxf(fmaf(acc[i][1], scy, shy), 0.f);
      o.z = fmaxf(fmaf(acc[i][2], scz, shz), 0.f);
      o.w = fmaxf(fmaf(acc[i][3], scw, shw), 0.f);
      *reinterpret_cast<float4*>(out + (size_t)gr * ldo + c0) = o;
    }
  }
}

// ------------------------------------------------------ fused classifier
// z = relu(jk @ Wc1 + bc1)  [N,64];  out = z @ Wc2 + bc2  [N,2]
// Tile 64 rows; K=384 in 3 chunks of 128 staged in LDS. 256 threads:
// thread = 8 rows x 2 cols for z. Then z tile -> padded LDS -> tiny GEMM.
__global__ __launch_bounds__(256) void classifier_kernel(
    const float* __restrict__ jk, const float* __restrict__ Wc1,
    const float* __restrict__ bc1, const float* __restrict__ Wc2,
    const float* __restrict__ bc2, float* __restrict__ out, int n) {
  __shared__ float sJ[64][DD];
  __shared__ float sZ[64][65];
  int t = threadIdx.x;
  int row0 = blockIdx.x * 64;
  int tx = t & 31, ty = t >> 5;
  int c0 = tx * 2, r0 = ty * 8;
  float acc[8][2];
#pragma unroll
  for (int i = 0; i < 8; ++i) acc[i][0] = acc[i][1] = 0.f;

  for (int kc = 0; kc < 3 * DD; kc += DD) {
    __syncthreads();
#pragma unroll
    for (int it = 0; it < 8; ++it) {
      int idx = it * 256 + t;
      int r = idx >> 5;
      int c4 = (idx & 31) * 4;
      int gr = row0 + r;
      float4 v = {0.f, 0.f, 0.f, 0.f};
      if (gr < n) v = *reinterpret_cast<const float4*>(jk + (size_t)gr * (3 * DD) + kc + c4);
      *reinterpret_cast<float4*>(&sJ[r][c4]) = v;
    }
    __syncthreads();
    for (int k = 0; k < DD; ++k) {
      float2 w = *reinterpret_cast<const float2*>(Wc1 + (size_t)(kc + k) * 64 + c0);
#pragma unroll
      for (int i = 0; i < 8; ++i) {
        float jv = sJ[r0 + i][k];
        acc[i][0] = fmaf(jv, w.x, acc[i][0]);
        acc[i][1] = fmaf(jv, w.y, acc[i][1]);
      }
    }
  }

  float2 b1 = *reinterpret_cast<const float2*>(bc1 + c0);
#pragma unroll
  for (int i = 0; i < 8; ++i) {
    sZ[r0 + i][c0] = fmaxf(acc[i][0] + b1.x, 0.f);
    sZ[r0 + i][c0 + 1] = fmaxf(acc[i][1] + b1.y, 0.f);
  }
  __syncthreads();

  if (t < 128) {
    int r = t >> 1, j = t & 1;
    int gr = row0 + r;
    if (gr < n) {
      float s = bc2[j];
#pragma unroll
      for (int c = 0; c < 64; ++c) s = fmaf(sZ[r][c], Wc2[c * 2 + j], s);
      out[(size_t)gr * 2 + j] = s;
    }
  }
}

// ----------------------------------------------------------------- launch

extern "C" void kernel_launch(void* const* d_in, const int* in_sizes, int n_in,
                              void* d_out, int out_size, void* d_ws, size_t ws_size,
                              hipStream_t stream) {
  const float* x = (const float*)d_in[0];
  const int* ei = (const int*)d_in[1];
  const float* Wl = (const float*)d_in[2];
  const float* bl = (const float*)d_in[3];
  const float* Wr = (const float*)d_in[4];
  const float* gamma = (const float*)d_in[5];
  const float* beta = (const float*)d_in[6];
  const float* rmean = (const float*)d_in[7];
  const float* rvar = (const float*)d_in[8];
  const float* Wc1 = (const float*)d_in[9];
  const float* bc1 = (const float*)d_in[10];
  const float* Wc2 = (const float*)d_in[11];
  const float* bc2 = (const float*)d_in[12];
  float* out = (float*)d_out;

  const int N = in_sizes[0] / DD;
  const int E = in_sizes[1] / 2;
  const int* src = ei;
  const int* dst = ei + E;

  auto align = [](size_t v) { return (v + 255) & ~(size_t)255; };
  char* ws = (char*)d_ws;
  size_t off = 0;
  int* deg = (int*)(ws + off);      off = align(off + sizeof(int) * (size_t)N);
  int* row_start = (int*)(ws + off); off = align(off + sizeof(int) * (size_t)(N + 1));
  int* cursor = (int*)(ws + off);   off = align(off + sizeof(int) * (size_t)N);
  int* col = (int*)(ws + off);      off = align(off + sizeof(int) * (size_t)E);
  float* inv_deg = (float*)(ws + off); off = align(off + sizeof(float) * (size_t)N);
  float* agg = (float*)(ws + off);  off = align(off + sizeof(float) * (size_t)N * DD);
  float* jk = (float*)(ws + off);   off = align(off + sizeof(float) * (size_t)N * 3 * DD);

  // CSR build (per launch; ws is re-poisoned every call)
  zero_int_kernel<<<(N + 255) / 256, 256, 0, stream>>>(deg, N);
  degree_kernel<<<(E + 255) / 256, 256, 0, stream>>>(dst, deg, E);
  scan_kernel<<<1, 1024, 0, stream>>>(deg, row_start, cursor, inv_deg, N);
  fill_kernel<<<(E + 255) / 256, 256, 0, stream>>>(src, dst, cursor, col, E);

  int nTiles = (N + 63) / 64;
  for (int i = 0; i < 3; ++i) {
    const float* hin = (i == 0) ? x : (jk + (size_t)(i - 1) * DD);
    int ldh = (i == 0) ? DD : 3 * DD;
    agg_kernel<<<(N + 3) / 4, 256, 0, stream>>>(hin, ldh, row_start, col, inv_deg, agg, N);
    layer_gemm<<<nTiles, 256, 0, stream>>>(
        hin, ldh, agg, Wl + (size_t)i * DD * DD, bl + (size_t)i * DD,
        Wr + (size_t)i * DD * DD, gamma + (size_t)i * DD, beta + (size_t)i * DD,
        rmean + (size_t)i * DD, rvar + (size_t)i * DD, jk + (size_t)i * DD, 3 * DD, N);
  }
  classifier_kernel<<<nTiles, 256, 0, stream>>>(jk, Wc1, bc1, Wc2, bc2, out, N);
}

// Round 2
// 697.697 us; speedup vs baseline: 1.2109x; 1.2109x over previous
//
#include <hip/hip_runtime.h>
#include <cstdint>
#include <cstddef>

#define DD 128
#define EPSV 1e-5f

// ---------------------------------------------------------------- utilities

__global__ void zero_int_kernel(int* __restrict__ p, int n) {
  int i = blockIdx.x * blockDim.x + threadIdx.x;
  if (i < n) p[i] = 0;
}

__global__ void degree_kernel(const int* __restrict__ dst, int* __restrict__ deg, int E) {
  int e = blockIdx.x * blockDim.x + threadIdx.x;
  if (e < E) atomicAdd(&deg[dst[e]], 1);
}

__global__ __launch_bounds__(1024) void scan_kernel(const int* __restrict__ deg,
                                                    int* __restrict__ row_start,
                                                    int* __restrict__ cursor,
                                                    float* __restrict__ inv_deg, int n) {
  __shared__ int wsum[16];
  __shared__ int wpref[16];
  __shared__ int s_running;
  __shared__ int s_total;
  int t = threadIdx.x;
  int lane = t & 63, wid = t >> 6;
  if (t == 0) s_running = 0;
  __syncthreads();
  for (int base = 0; base < n; base += 1024) {
    int i = base + t;
    int v = (i < n) ? deg[i] : 0;
    int sc = v;
#pragma unroll
    for (int off = 1; off < 64; off <<= 1) {
      int u = __shfl_up(sc, off, 64);
      if (lane >= off) sc += u;
    }
    if (lane == 63) wsum[wid] = sc;
    __syncthreads();
    if (t == 0) {
      int a = 0;
#pragma unroll
      for (int w = 0; w < 16; ++w) { wpref[w] = a; a += wsum[w]; }
      s_total = a;
    }
    __syncthreads();
    int run = s_running;
    int excl = run + wpref[wid] + (sc - v);
    if (i < n) {
      row_start[i] = excl;
      cursor[i] = excl;
      inv_deg[i] = 1.0f / fmaxf((float)v, 1.0f);
    }
    __syncthreads();
    if (t == 0) s_running = run + s_total;
    __syncthreads();
  }
  if (t == 0) row_start[n] = s_running;
}

__global__ void fill_kernel(const int* __restrict__ src, const int* __restrict__ dst,
                            int* cursor, int* __restrict__ col, int E) {
  int e = blockIdx.x * blockDim.x + threadIdx.x;
  if (e < E) {
    int d = dst[e];
    int p = atomicAdd(&cursor[d], 1);
    col[p] = src[e];
  }
}

// ------------------------------------------------------------- aggregation
// One wave per node. Lanes split into two halves of 32; each half gathers one
// edge's h-row per step (32 lanes x float4 = 512B coalesced). Col indices are
// batch-loaded into lanes and distributed via shuffle (no per-edge uniform
// load on the critical path). Two accumulators per half for MLP.
__global__ __launch_bounds__(256) void agg_kernel(const float* __restrict__ h, int ldh,
                                                  const int* __restrict__ row_start,
                                                  const int* __restrict__ col,
                                                  const float* __restrict__ inv_deg,
                                                  float* __restrict__ agg, int n) {
  int wib = threadIdx.x >> 6;
  int lane = threadIdx.x & 63;
  int node = blockIdx.x * 4 + wib;
  if (node >= n) return;
  int beg = row_start[node];
  int end = row_start[node + 1];
  int half = lane >> 5;
  int l32 = lane & 31;
  int c4 = l32 * 4;
  float4 acc0 = {0.f, 0.f, 0.f, 0.f};
  float4 acc1 = {0.f, 0.f, 0.f, 0.f};
  for (int j0 = beg; j0 < end; j0 += 64) {
    int cnt = min(64, end - j0);
    int cidx = col[j0 + min(lane, cnt - 1)];
    for (int j = 0; j < cnt; j += 4) {
      int e0 = j + half;
      int e1 = j + 2 + half;
      int s0 = __shfl(cidx, e0 < cnt ? e0 : 0);
      int s1 = __shfl(cidx, e1 < cnt ? e1 : 0);
      if (e0 < cnt) {
        float4 v = *reinterpret_cast<const float4*>(h + (size_t)s0 * ldh + c4);
        acc0.x += v.x; acc0.y += v.y; acc0.z += v.z; acc0.w += v.w;
      }
      if (e1 < cnt) {
        float4 v = *reinterpret_cast<const float4*>(h + (size_t)s1 * ldh + c4);
        acc1.x += v.x; acc1.y += v.y; acc1.z += v.z; acc1.w += v.w;
      }
    }
  }
  acc0.x += acc1.x; acc0.y += acc1.y; acc0.z += acc1.z; acc0.w += acc1.w;
  int partner = (lane + 32) & 63;
  float ox = acc0.x + __shfl(acc0.x, partner);
  float oy = acc0.y + __shfl(acc0.y, partner);
  float oz = acc0.z + __shfl(acc0.z, partner);
  float ow = acc0.w + __shfl(acc0.w, partner);
  if (lane < 32) {
    float w = inv_deg[node];
    float4 o;
    o.x = ox * w; o.y = oy * w; o.z = oz * w; o.w = ow * w;
    *reinterpret_cast<float4*>(agg + (size_t)node * DD + c4) = o;
  }
}

// ------------------------------------------------- fused layer GEMM + BN + ReLU
// out[r,c] = relu(BN(agg[r,:]@Wl[:,c] + bl[c] + h[r,:]@Wr[:,c]))
// Tile 64 rows x 128 cols, K=128. A/H tiles staged once in LDS (64KB).
// W staged in LDS in k-chunks of 8 (Wl+Wr = 8KB), double-buffered with
// register prefetch: no global-load latency inside the FMA loop.
// LDS = 80KB -> 2 blocks/CU.
__global__ __launch_bounds__(256) void layer_gemm(
    const float* __restrict__ hin, int ldh, const float* __restrict__ agg,
    const float* __restrict__ Wl, const float* __restrict__ bl,
    const float* __restrict__ Wr, const float* __restrict__ gamma,
    const float* __restrict__ beta, const float* __restrict__ rmean,
    const float* __restrict__ rvar, float* __restrict__ out, int ldo, int n) {
  __shared__ float sA[64][DD];
  __shared__ float sH[64][DD];
  __shared__ float sW[2][8][2][DD];
  int t = threadIdx.x;
  int row0 = blockIdx.x * 64;

  // stage A/H tiles (once per block)
#pragma unroll
  for (int it = 0; it < 8; ++it) {
    int idx = it * 256 + t;
    int r = idx >> 5;
    int cc = (idx & 31) * 4;
    int gr = row0 + r;
    float4 va = {0.f, 0.f, 0.f, 0.f};
    float4 vh = {0.f, 0.f, 0.f, 0.f};
    if (gr < n) {
      va = *reinterpret_cast<const float4*>(agg + (size_t)gr * DD + cc);
      vh = *reinterpret_cast<const float4*>(hin + (size_t)gr * ldh + cc);
    }
    *reinterpret_cast<float4*>(&sA[r][cc]) = va;
    *reinterpret_cast<float4*>(&sH[r][cc]) = vh;
  }

  // per-thread W staging slots (2 float4 per chunk)
  int f1 = t + 256;
  int k_0 = t >> 6, rem0 = t & 63, mat0 = rem0 >> 5, wc0 = (rem0 & 31) * 4;
  int k_1 = f1 >> 6, rem1 = f1 & 63, mat1 = rem1 >> 5, wc1 = (rem1 & 31) * 4;
  const float* Wm0 = mat0 ? Wr : Wl;
  const float* Wm1 = mat1 ? Wr : Wl;

  float4 p0 = *reinterpret_cast<const float4*>(Wm0 + (size_t)k_0 * DD + wc0);
  float4 p1 = *reinterpret_cast<const float4*>(Wm1 + (size_t)k_1 * DD + wc1);

  int tx = t & 31, ty = t >> 5;
  int c0 = tx * 4, r0 = ty * 8;
  float acc[8][4];
#pragma unroll
  for (int i = 0; i < 8; ++i) acc[i][0] = acc[i][1] = acc[i][2] = acc[i][3] = 0.f;

  for (int c = 0; c < 16; ++c) {
    int buf = c & 1;
    *reinterpret_cast<float4*>(&sW[buf][k_0][mat0][wc0]) = p0;
    *reinterpret_cast<float4*>(&sW[buf][k_1][mat1][wc1]) = p1;
    __syncthreads();
    if (c + 1 < 16) {
      int kn = (c + 1) * 8;
      p0 = *reinterpret_cast<const float4*>(Wm0 + (size_t)(kn + k_0) * DD + wc0);
      p1 = *reinterpret_cast<const float4*>(Wm1 + (size_t)(kn + k_1) * DD + wc1);
    }
    int kbase = c * 8;
#pragma unroll
    for (int kp = 0; kp < 2; ++kp) {
      float a4[8][4] __attribute__((aligned(16)));
      float h4[8][4] __attribute__((aligned(16)));
#pragma unroll
      for (int i = 0; i < 8; ++i) {
        *reinterpret_cast<float4*>(a4[i]) =
            *reinterpret_cast<const float4*>(&sA[r0 + i][kbase + kp * 4]);
        *reinterpret_cast<float4*>(h4[i]) =
            *reinterpret_cast<const float4*>(&sH[r0 + i][kbase + kp * 4]);
      }
#pragma unroll
      for (int kk = 0; kk < 4; ++kk) {
        float4 wl = *reinterpret_cast<const float4*>(&sW[buf][kp * 4 + kk][0][c0]);
        float4 wr = *reinterpret_cast<const float4*>(&sW[buf][kp * 4 + kk][1][c0]);
#pragma unroll
        for (int i = 0; i < 8; ++i) {
          acc[i][0] = fmaf(a4[i][kk], wl.x, fmaf(h4[i][kk], wr.x, acc[i][0]));
          acc[i][1] = fmaf(a4[i][kk], wl.y, fmaf(h4[i][kk], wr.y, acc[i][1]));
          acc[i][2] = fmaf(a4[i][kk], wl.z, fmaf(h4[i][kk], wr.z, acc[i][2]));
          acc[i][3] = fmaf(a4[i][kk], wl.w, fmaf(h4[i][kk], wr.w, acc[i][3]));
        }
      }
    }
  }

  float4 blv = *reinterpret_cast<const float4*>(bl + c0);
  float4 gm = *reinterpret_cast<const float4*>(gamma + c0);
  float4 bt = *reinterpret_cast<const float4*>(beta + c0);
  float4 rm = *reinterpret_cast<const float4*>(rmean + c0);
  float4 rv = *reinterpret_cast<const float4*>(rvar + c0);
  float scx = gm.x * rsqrtf(rv.x + EPSV);
  float scy = gm.y * rsqrtf(rv.y + EPSV);
  float scz = gm.z * rsqrtf(rv.z + EPSV);
  float scw = gm.w * rsqrtf(rv.w + EPSV);
  float shx = (blv.x - rm.x) * scx + bt.x;
  float shy = (blv.y - rm.y) * scy + bt.y;
  float shz = (blv.z - rm.z) * scz + bt.z;
  float shw = (blv.w - rm.w) * scw + bt.w;

#pragma unroll
  for (int i = 0; i < 8; ++i) {
    int gr = row0 + r0 + i;
    if (gr < n) {
      float4 o;
      o.x = fmaxf(fmaf(acc[i][0], scx, shx), 0.f);
      o.y = fmaxf(fmaf(acc[i][1], scy, shy), 0.f);
      o.z = fmaxf(fmaf(acc[i][2], scz, shz), 0.f);
      o.w = fmaxf(fmaf(acc[i][3], scw, shw), 0.f);
      *reinterpret_cast<float4*>(out + (size_t)gr * ldo + c0) = o;
    }
  }
}

// ------------------------------------------------------ fused classifier
// z = relu(jk @ Wc1 + bc1)  [N,64];  out = z @ Wc2 + bc2  [N,2]
// K=384 in 3 chunks of 128; both jk-tile AND Wc1-chunk staged in LDS
// (32KB + 32KB = 64KB -> 2 blocks/CU). sZ overlays sJ after the main GEMM.
__global__ __launch_bounds__(256) void classifier_kernel(
    const float* __restrict__ jk, const float* __restrict__ Wc1,
    const float* __restrict__ bc1, const float* __restrict__ Wc2,
    const float* __restrict__ bc2, float* __restrict__ out, int n) {
  __shared__ float sJ[64][DD];
  __shared__ float sW1[DD][64];
  int t = threadIdx.x;
  int row0 = blockIdx.x * 64;
  int tx = t & 31, ty = t >> 5;
  int c0 = tx * 2, r0 = ty * 8;
  float acc[8][2];
#pragma unroll
  for (int i = 0; i < 8; ++i) acc[i][0] = acc[i][1] = 0.f;

  for (int kc = 0; kc < 3 * DD; kc += DD) {
    __syncthreads();
#pragma unroll
    for (int it = 0; it < 8; ++it) {
      int idx = it * 256 + t;
      int r = idx >> 5;
      int cc = (idx & 31) * 4;
      int gr = row0 + r;
      float4 v = {0.f, 0.f, 0.f, 0.f};
      if (gr < n) v = *reinterpret_cast<const float4*>(jk + (size_t)gr * (3 * DD) + kc + cc);
      *reinterpret_cast<float4*>(&sJ[r][cc]) = v;
    }
#pragma unroll
    for (int it = 0; it < 8; ++it) {
      int idx = it * 256 + t;
      int k = idx >> 4;
      int cc = (idx & 15) * 4;
      float4 w = *reinterpret_cast<const float4*>(Wc1 + (size_t)(kc + k) * 64 + cc);
      *reinterpret_cast<float4*>(&sW1[k][cc]) = w;
    }
    __syncthreads();
#pragma unroll 4
    for (int k = 0; k < DD; ++k) {
      float2 w = *reinterpret_cast<const float2*>(&sW1[k][c0]);
#pragma unroll
      for (int i = 0; i < 8; ++i) {
        float jv = sJ[r0 + i][k];
        acc[i][0] = fmaf(jv, w.x, acc[i][0]);
        acc[i][1] = fmaf(jv, w.y, acc[i][1]);
      }
    }
  }

  __syncthreads();  // all sJ reads done; safe to overlay sZ
  float(*sZ)[65] = reinterpret_cast<float(*)[65]>(&sJ[0][0]);
  float2 b1 = *reinterpret_cast<const float2*>(bc1 + c0);
#pragma unroll
  for (int i = 0; i < 8; ++i) {
    sZ[r0 + i][c0] = fmaxf(acc[i][0] + b1.x, 0.f);
    sZ[r0 + i][c0 + 1] = fmaxf(acc[i][1] + b1.y, 0.f);
  }
  __syncthreads();

  if (t < 128) {
    int r = t >> 1, j = t & 1;
    int gr = row0 + r;
    if (gr < n) {
      float s = bc2[j];
#pragma unroll
      for (int c = 0; c < 64; ++c) s = fmaf(sZ[r][c], Wc2[c * 2 + j], s);
      out[(size_t)gr * 2 + j] = s;
    }
  }
}

// ----------------------------------------------------------------- launch

extern "C" void kernel_launch(void* const* d_in, const int* in_sizes, int n_in,
                              void* d_out, int out_size, void* d_ws, size_t ws_size,
                              hipStream_t stream) {
  const float* x = (const float*)d_in[0];
  const int* ei = (const int*)d_in[1];
  const float* Wl = (const float*)d_in[2];
  const float* bl = (const float*)d_in[3];
  const float* Wr = (const float*)d_in[4];
  const float* gamma = (const float*)d_in[5];
  const float* beta = (const float*)d_in[6];
  const float* rmean = (const float*)d_in[7];
  const float* rvar = (const float*)d_in[8];
  const float* Wc1 = (const float*)d_in[9];
  const float* bc1 = (const float*)d_in[10];
  const float* Wc2 = (const float*)d_in[11];
  const float* bc2 = (const float*)d_in[12];
  float* out = (float*)d_out;

  const int N = in_sizes[0] / DD;
  const int E = in_sizes[1] / 2;
  const int* src = ei;
  const int* dst = ei + E;

  auto align = [](size_t v) { return (v + 255) & ~(size_t)255; };
  char* ws = (char*)d_ws;
  size_t off = 0;
  int* deg = (int*)(ws + off);      off = align(off + sizeof(int) * (size_t)N);
  int* row_start = (int*)(ws + off); off = align(off + sizeof(int) * (size_t)(N + 1));
  int* cursor = (int*)(ws + off);   off = align(off + sizeof(int) * (size_t)N);
  int* col = (int*)(ws + off);      off = align(off + sizeof(int) * (size_t)E);
  float* inv_deg = (float*)(ws + off); off = align(off + sizeof(float) * (size_t)N);
  float* agg = (float*)(ws + off);  off = align(off + sizeof(float) * (size_t)N * DD);
  float* jk = (float*)(ws + off);   off = align(off + sizeof(float) * (size_t)N * 3 * DD);

  zero_int_kernel<<<(N + 255) / 256, 256, 0, stream>>>(deg, N);
  degree_kernel<<<(E + 255) / 256, 256, 0, stream>>>(dst, deg, E);
  scan_kernel<<<1, 1024, 0, stream>>>(deg, row_start, cursor, inv_deg, N);
  fill_kernel<<<(E + 255) / 256, 256, 0, stream>>>(src, dst, cursor, col, E);

  int nTiles = (N + 63) / 64;
  for (int i = 0; i < 3; ++i) {
    const float* hin = (i == 0) ? x : (jk + (size_t)(i - 1) * DD);
    int ldh = (i == 0) ? DD : 3 * DD;
    agg_kernel<<<(N + 3) / 4, 256, 0, stream>>>(hin, ldh, row_start, col, inv_deg, agg, N);
    layer_gemm<<<nTiles, 256, 0, stream>>>(
        hin, ldh, agg, Wl + (size_t)i * DD * DD, bl + (size_t)i * DD,
        Wr + (size_t)i * DD * DD, gamma + (size_t)i * DD, beta + (size_t)i * DD,
        rmean + (size_t)i * DD, rvar + (size_t)i * DD, jk + (size_t)i * DD, 3 * DD, N);
  }
  classifier_kernel<<<nTiles, 256, 0, stream>>>(jk, Wc1, bc1, Wc2, bc2, out, N);
}

// Round 3
// 511.600 us; speedup vs baseline: 1.6513x; 1.3638x over previous
//
#include <hip/hip_runtime.h>
#include <cstdint>
#include <cstddef>

#define DD 128
#define EPSV 1e-5f

typedef __attribute__((ext_vector_type(8))) short bf16x8;
typedef __attribute__((ext_vector_type(4))) float f32x4;
#define MFMA(a, b, c) __builtin_amdgcn_mfma_f32_16x16x32_bf16(a, b, c, 0, 0, 0)

__device__ inline unsigned short f2bf_rne(float f) {
  unsigned u = __float_as_uint(f);
  unsigned r = u + 0x7fffu + ((u >> 16) & 1u);
  return (unsigned short)(r >> 16);
}

__device__ inline void split8(const float* s, bf16x8& hi, bf16x8& lo) {
#pragma unroll
  for (int j = 0; j < 8; ++j) {
    float f = s[j];
    unsigned short h = f2bf_rne(f);
    float fh = __uint_as_float((unsigned)h << 16);
    hi[j] = (short)h;
    lo[j] = (short)f2bf_rne(f - fh);
  }
}

// ---------------------------------------------------------------- utilities

__global__ void zero_int_kernel(int* __restrict__ p, int n) {
  int i = blockIdx.x * blockDim.x + threadIdx.x;
  if (i < n) p[i] = 0;
}

__global__ void degree_kernel(const int* __restrict__ dst, int* __restrict__ deg, int E) {
  int e = blockIdx.x * blockDim.x + threadIdx.x;
  if (e < E) atomicAdd(&deg[dst[e]], 1);
}

__global__ __launch_bounds__(1024) void scan_kernel(const int* __restrict__ deg,
                                                    int* __restrict__ row_start,
                                                    int* __restrict__ cursor,
                                                    float* __restrict__ inv_deg, int n) {
  __shared__ int wsum[16];
  __shared__ int wpref[16];
  __shared__ int s_running;
  __shared__ int s_total;
  int t = threadIdx.x;
  int lane = t & 63, wid = t >> 6;
  if (t == 0) s_running = 0;
  __syncthreads();
  for (int base = 0; base < n; base += 1024) {
    int i = base + t;
    int v = (i < n) ? deg[i] : 0;
    int sc = v;
#pragma unroll
    for (int off = 1; off < 64; off <<= 1) {
      int u = __shfl_up(sc, off, 64);
      if (lane >= off) sc += u;
    }
    if (lane == 63) wsum[wid] = sc;
    __syncthreads();
    if (t == 0) {
      int a = 0;
#pragma unroll
      for (int w = 0; w < 16; ++w) { wpref[w] = a; a += wsum[w]; }
      s_total = a;
    }
    __syncthreads();
    int run = s_running;
    int excl = run + wpref[wid] + (sc - v);
    if (i < n) {
      row_start[i] = excl;
      cursor[i] = excl;
      inv_deg[i] = 1.0f / fmaxf((float)v, 1.0f);
    }
    __syncthreads();
    if (t == 0) s_running = run + s_total;
    __syncthreads();
  }
  if (t == 0) row_start[n] = s_running;
}

__global__ void fill_kernel(const int* __restrict__ src, const int* __restrict__ dst,
                            int* cursor, int* __restrict__ col, int E) {
  int e = blockIdx.x * blockDim.x + threadIdx.x;
  if (e < E) {
    int d = dst[e];
    int p = atomicAdd(&cursor[d], 1);
    col[p] = src[e];
  }
}

// -------------------------------------------------- weight prep (bf16 split)
// Fragment-ordered layout so the GEMM's B-loads are 1KB contiguous per wave.
// layer weights: f[layer][mat][part][(ks*8+nt)*64+lane] each a 16B frag.
__global__ __launch_bounds__(256) void prep_layer_w(const float* __restrict__ Wl,
                                                    const float* __restrict__ Wr,
                                                    bf16x8* __restrict__ f) {
  int idx = blockIdx.x * 256 + threadIdx.x;  // [0, 12288)
  int lane = idx & 63;
  int ksnt = (idx >> 6) & 31;  // ks*8+nt
  int mat = (idx >> 11) & 1;
  int layer = idx >> 12;
  int ks = ksnt >> 3, nt = ksnt & 7;
  int nn = nt * 16 + (lane & 15);
  int k0 = ks * 32 + (lane >> 4) * 8;
  const float* W = (mat ? Wr : Wl) + (size_t)layer * DD * DD;
  float v[8];
#pragma unroll
  for (int j = 0; j < 8; ++j) v[j] = W[(size_t)(k0 + j) * DD + nn];
  bf16x8 hi, lo;
  split8(v, hi, lo);
  size_t base = (size_t)((layer * 2 + mat) * 2) * 2048 + (size_t)ksnt * 64 + lane;
  f[base] = hi;
  f[base + 2048] = lo;
}

// classifier Wc1 [384][64]: f[part][(ks*4+nt)*64+lane], ks<12, nt<4
__global__ __launch_bounds__(256) void prep_cls_w(const float* __restrict__ Wc1,
                                                  bf16x8* __restrict__ f) {
  int idx = blockIdx.x * 256 + threadIdx.x;  // [0, 3072)
  if (idx >= 3072) return;
  int lane = idx & 63;
  int ksnt = idx >> 6;
  int ks = ksnt >> 2, nt = ksnt & 3;
  int nn = nt * 16 + (lane & 15);
  int k0 = ks * 32 + (lane >> 4) * 8;
  float v[8];
#pragma unroll
  for (int j = 0; j < 8; ++j) v[j] = Wc1[(size_t)(k0 + j) * 64 + nn];
  bf16x8 hi, lo;
  split8(v, hi, lo);
  f[idx] = hi;
  f[idx + 3072] = lo;
}

// ------------------------------------------------------------- aggregation
__global__ __launch_bounds__(256) void agg_kernel(const float* __restrict__ h, int ldh,
                                                  const int* __restrict__ row_start,
                                                  const int* __restrict__ col,
                                                  const float* __restrict__ inv_deg,
                                                  float* __restrict__ agg, int n) {
  int wib = threadIdx.x >> 6;
  int lane = threadIdx.x & 63;
  int node = blockIdx.x * 4 + wib;
  if (node >= n) return;
  int beg = row_start[node];
  int end = row_start[node + 1];
  int half = lane >> 5;
  int l32 = lane & 31;
  int c4 = l32 * 4;
  float4 acc0 = {0.f, 0.f, 0.f, 0.f};
  float4 acc1 = {0.f, 0.f, 0.f, 0.f};
  for (int j0 = beg; j0 < end; j0 += 64) {
    int cnt = min(64, end - j0);
    int cidx = col[j0 + min(lane, cnt - 1)];
    for (int j = 0; j < cnt; j += 4) {
      int e0 = j + half;
      int e1 = j + 2 + half;
      int s0 = __shfl(cidx, e0 < cnt ? e0 : 0);
      int s1 = __shfl(cidx, e1 < cnt ? e1 : 0);
      if (e0 < cnt) {
        float4 v = *reinterpret_cast<const float4*>(h + (size_t)s0 * ldh + c4);
        acc0.x += v.x; acc0.y += v.y; acc0.z += v.z; acc0.w += v.w;
      }
      if (e1 < cnt) {
        float4 v = *reinterpret_cast<const float4*>(h + (size_t)s1 * ldh + c4);
        acc1.x += v.x; acc1.y += v.y; acc1.z += v.z; acc1.w += v.w;
      }
    }
  }
  acc0.x += acc1.x; acc0.y += acc1.y; acc0.z += acc1.z; acc0.w += acc1.w;
  int partner = (lane + 32) & 63;
  float ox = acc0.x + __shfl(acc0.x, partner);
  float oy = acc0.y + __shfl(acc0.y, partner);
  float oz = acc0.z + __shfl(acc0.z, partner);
  float ow = acc0.w + __shfl(acc0.w, partner);
  if (lane < 32) {
    float w = inv_deg[node];
    float4 o;
    o.x = ox * w; o.y = oy * w; o.z = oz * w; o.w = ow * w;
    *reinterpret_cast<float4*>(agg + (size_t)node * DD + c4) = o;
  }
}

// ---------------------------------------- MFMA layer GEMM + BN + ReLU (no LDS)
// out = relu(BN(agg@Wl + bl + hin@Wr)). Block = 64 rows, wave = 16 rows.
// bf16 hi/lo split, 3-term: err ~2^-16. A/H frags converted in-register;
// B frags from fragment-ordered prefab (coalesced 1KB wave loads, L2-hot).
__global__ __launch_bounds__(256) void layer_gemm_mfma(
    const float* __restrict__ hin, int ldh, const float* __restrict__ agg,
    const bf16x8* __restrict__ Blh_g, const bf16x8* __restrict__ Bll_g,
    const bf16x8* __restrict__ Brh_g, const bf16x8* __restrict__ Brl_g,
    const float* __restrict__ bl, const float* __restrict__ gamma,
    const float* __restrict__ beta, const float* __restrict__ rmean,
    const float* __restrict__ rvar, float* __restrict__ out, int ldo, int n) {
  int t = threadIdx.x;
  int w = t >> 6, lane = t & 63;
  int lane16 = lane & 15, quad = lane >> 4;
  int row0 = blockIdx.x * 64;
  int m = row0 + w * 16 + lane16;
  bool valid = m < n;
  size_t mrow = (size_t)(valid ? m : 0);
  const float* ap = agg + mrow * DD + quad * 8;
  const float* hp = hin + mrow * (size_t)ldh + quad * 8;

  bf16x8 Ah[4], Al[4], Hh[4], Hl[4];
#pragma unroll
  for (int ks = 0; ks < 4; ++ks) {
    float a8[8] __attribute__((aligned(16)));
    float h8[8] __attribute__((aligned(16)));
    if (valid) {
      *reinterpret_cast<float4*>(a8) = *reinterpret_cast<const float4*>(ap + ks * 32);
      *reinterpret_cast<float4*>(a8 + 4) = *reinterpret_cast<const float4*>(ap + ks * 32 + 4);
      *reinterpret_cast<float4*>(h8) = *reinterpret_cast<const float4*>(hp + ks * 32);
      *reinterpret_cast<float4*>(h8 + 4) = *reinterpret_cast<const float4*>(hp + ks * 32 + 4);
    } else {
#pragma unroll
      for (int j = 0; j < 8; ++j) { a8[j] = 0.f; h8[j] = 0.f; }
    }
    split8(a8, Ah[ks], Al[ks]);
    split8(h8, Hh[ks], Hl[ks]);
  }

  f32x4 acc[8];
#pragma unroll
  for (int nt = 0; nt < 8; ++nt) acc[nt] = (f32x4){0.f, 0.f, 0.f, 0.f};

#pragma unroll
  for (int ks = 0; ks < 4; ++ks) {
    int fb = ks * 8 * 64 + lane;
    bf16x8 B0[8], B1[8];
#pragma unroll
    for (int nt = 0; nt < 8; ++nt) B0[nt] = Blh_g[fb + nt * 64];
#pragma unroll
    for (int nt = 0; nt < 8; ++nt) acc[nt] = MFMA(Ah[ks], B0[nt], acc[nt]);
#pragma unroll
    for (int nt = 0; nt < 8; ++nt) B1[nt] = Bll_g[fb + nt * 64];
#pragma unroll
    for (int nt = 0; nt < 8; ++nt) acc[nt] = MFMA(Al[ks], B0[nt], acc[nt]);
#pragma unroll
    for (int nt = 0; nt < 8; ++nt) acc[nt] = MFMA(Ah[ks], B1[nt], acc[nt]);
#pragma unroll
    for (int nt = 0; nt < 8; ++nt) B0[nt] = Brh_g[fb + nt * 64];
#pragma unroll
    for (int nt = 0; nt < 8; ++nt) acc[nt] = MFMA(Hh[ks], B0[nt], acc[nt]);
#pragma unroll
    for (int nt = 0; nt < 8; ++nt) B1[nt] = Brl_g[fb + nt * 64];
#pragma unroll
    for (int nt = 0; nt < 8; ++nt) acc[nt] = MFMA(Hl[ks], B0[nt], acc[nt]);
#pragma unroll
    for (int nt = 0; nt < 8; ++nt) acc[nt] = MFMA(Hh[ks], B1[nt], acc[nt]);
  }

#pragma unroll
  for (int nt = 0; nt < 8; ++nt) {
    int c = nt * 16 + lane16;
    float sc = gamma[c] * rsqrtf(rvar[c] + EPSV);
    float sh = (bl[c] - rmean[c]) * sc + beta[c];
#pragma unroll
    for (int r = 0; r < 4; ++r) {
      int orow = row0 + w * 16 + quad * 4 + r;
      if (orow < n)
        out[(size_t)orow * ldo + c] = fmaxf(fmaf(acc[nt][r], sc, sh), 0.f);
    }
  }
}

// ------------------------------------------------------ MFMA classifier
__global__ __launch_bounds__(256) void classifier_mfma(
    const float* __restrict__ jk, const bf16x8* __restrict__ Bh_g,
    const bf16x8* __restrict__ Bl_g, const float* __restrict__ bc1,
    const float* __restrict__ Wc2, const float* __restrict__ bc2,
    float* __restrict__ out, int n) {
  __shared__ float sZ[64][65];
  int t = threadIdx.x;
  int w = t >> 6, lane = t & 63;
  int lane16 = lane & 15, quad = lane >> 4;
  int row0 = blockIdx.x * 64;
  int m = row0 + w * 16 + lane16;
  bool valid = m < n;
  const float* jp = jk + (size_t)(valid ? m : 0) * (3 * DD) + quad * 8;

  f32x4 acc[4];
#pragma unroll
  for (int nt = 0; nt < 4; ++nt) acc[nt] = (f32x4){0.f, 0.f, 0.f, 0.f};

#pragma unroll
  for (int ks = 0; ks < 12; ++ks) {
    float a8[8] __attribute__((aligned(16)));
    if (valid) {
      *reinterpret_cast<float4*>(a8) = *reinterpret_cast<const float4*>(jp + ks * 32);
      *reinterpret_cast<float4*>(a8 + 4) = *reinterpret_cast<const float4*>(jp + ks * 32 + 4);
    } else {
#pragma unroll
      for (int j = 0; j < 8; ++j) a8[j] = 0.f;
    }
    bf16x8 Jh, Jl;
    split8(a8, Jh, Jl);
    int fb = ks * 4 * 64 + lane;
    bf16x8 B0[4], B1[4];
#pragma unroll
    for (int nt = 0; nt < 4; ++nt) B0[nt] = Bh_g[fb + nt * 64];
#pragma unroll
    for (int nt = 0; nt < 4; ++nt) acc[nt] = MFMA(Jh, B0[nt], acc[nt]);
#pragma unroll
    for (int nt = 0; nt < 4; ++nt) B1[nt] = Bl_g[fb + nt * 64];
#pragma unroll
    for (int nt = 0; nt < 4; ++nt) acc[nt] = MFMA(Jl, B0[nt], acc[nt]);
#pragma unroll
    for (int nt = 0; nt < 4; ++nt) acc[nt] = MFMA(Jh, B1[nt], acc[nt]);
  }

#pragma unroll
  for (int nt = 0; nt < 4; ++nt) {
    int c = nt * 16 + lane16;
    float b1 = bc1[c];
#pragma unroll
    for (int r = 0; r < 4; ++r)
      sZ[w * 16 + quad * 4 + r][c] = fmaxf(acc[nt][r] + b1, 0.f);
  }
  __syncthreads();

  if (t < 128) {
    int r = t >> 1, j = t & 1;
    int gr = row0 + r;
    if (gr < n) {
      float s = bc2[j];
#pragma unroll
      for (int c = 0; c < 64; ++c) s = fmaf(sZ[r][c], Wc2[c * 2 + j], s);
      out[(size_t)gr * 2 + j] = s;
    }
  }
}

// ----------------------------------------------------------------- launch

extern "C" void kernel_launch(void* const* d_in, const int* in_sizes, int n_in,
                              void* d_out, int out_size, void* d_ws, size_t ws_size,
                              hipStream_t stream) {
  const float* x = (const float*)d_in[0];
  const int* ei = (const int*)d_in[1];
  const float* Wl = (const float*)d_in[2];
  const float* bl = (const float*)d_in[3];
  const float* Wr = (const float*)d_in[4];
  const float* gamma = (const float*)d_in[5];
  const float* beta = (const float*)d_in[6];
  const float* rmean = (const float*)d_in[7];
  const float* rvar = (const float*)d_in[8];
  const float* Wc1 = (const float*)d_in[9];
  const float* bc1 = (const float*)d_in[10];
  const float* Wc2 = (const float*)d_in[11];
  const float* bc2 = (const float*)d_in[12];
  float* out = (float*)d_out;

  const int N = in_sizes[0] / DD;
  const int E = in_sizes[1] / 2;
  const int* src = ei;
  const int* dst = ei + E;

  auto align = [](size_t v) { return (v + 255) & ~(size_t)255; };
  char* ws = (char*)d_ws;
  size_t off = 0;
  int* deg = (int*)(ws + off);      off = align(off + sizeof(int) * (size_t)N);
  int* row_start = (int*)(ws + off); off = align(off + sizeof(int) * (size_t)(N + 1));
  int* cursor = (int*)(ws + off);   off = align(off + sizeof(int) * (size_t)N);
  int* col = (int*)(ws + off);      off = align(off + sizeof(int) * (size_t)E);
  float* inv_deg = (float*)(ws + off); off = align(off + sizeof(float) * (size_t)N);
  float* agg = (float*)(ws + off);  off = align(off + sizeof(float) * (size_t)N * DD);
  float* jk = (float*)(ws + off);   off = align(off + sizeof(float) * (size_t)N * 3 * DD);
  bf16x8* wf = (bf16x8*)(ws + off); off = align(off + (size_t)16 * 3 * 2 * 2 * 2048);
  bf16x8* wcf = (bf16x8*)(ws + off); off = align(off + (size_t)16 * 2 * 3072);

  zero_int_kernel<<<(N + 255) / 256, 256, 0, stream>>>(deg, N);
  degree_kernel<<<(E + 255) / 256, 256, 0, stream>>>(dst, deg, E);
  scan_kernel<<<1, 1024, 0, stream>>>(deg, row_start, cursor, inv_deg, N);
  fill_kernel<<<(E + 255) / 256, 256, 0, stream>>>(src, dst, cursor, col, E);
  prep_layer_w<<<48, 256, 0, stream>>>(Wl, Wr, wf);
  prep_cls_w<<<12, 256, 0, stream>>>(Wc1, wcf);

  int nTiles = (N + 63) / 64;
  for (int i = 0; i < 3; ++i) {
    const float* hin = (i == 0) ? x : (jk + (size_t)(i - 1) * DD);
    int ldh = (i == 0) ? DD : 3 * DD;
    agg_kernel<<<(N + 3) / 4, 256, 0, stream>>>(hin, ldh, row_start, col, inv_deg, agg, N);
    bf16x8* Wlf = wf + (size_t)(i * 2 + 0) * 2 * 2048;
    bf16x8* Wrf = wf + (size_t)(i * 2 + 1) * 2 * 2048;
    layer_gemm_mfma<<<nTiles, 256, 0, stream>>>(
        hin, ldh, agg, Wlf, Wlf + 2048, Wrf, Wrf + 2048,
        bl + (size_t)i * DD, gamma + (size_t)i * DD, beta + (size_t)i * DD,
        rmean + (size_t)i * DD, rvar + (size_t)i * DD, jk + (size_t)i * DD, 3 * DD, N);
  }
  classifier_mfma<<<nTiles, 256, 0, stream>>>(jk, wcf, wcf + 3072, bc1, Wc2, bc2, out, N);
}

// Round 4
// 417.350 us; speedup vs baseline: 2.0242x; 1.2258x over previous
//
#include <hip/hip_runtime.h>
#include <hip/hip_fp16.h>
#include <cstdint>
#include <cstddef>

#define DD 128
#define EPSV 1e-5f

typedef __attribute__((ext_vector_type(8))) short bf16x8;
typedef __attribute__((ext_vector_type(4))) float f32x4;
#define MFMA(a, b, c) __builtin_amdgcn_mfma_f32_16x16x32_bf16(a, b, c, 0, 0, 0)

__device__ inline unsigned short f2bf_rne(float f) {
  unsigned u = __float_as_uint(f);
  unsigned r = u + 0x7fffu + ((u >> 16) & 1u);
  return (unsigned short)(r >> 16);
}

__device__ inline void split8(const float* s, bf16x8& hi, bf16x8& lo) {
#pragma unroll
  for (int j = 0; j < 8; ++j) {
    float f = s[j];
    unsigned short h = f2bf_rne(f);
    float fh = __uint_as_float((unsigned)h << 16);
    hi[j] = (short)h;
    lo[j] = (short)f2bf_rne(f - fh);
  }
}

// ---------------------------------------------------------------- utilities

__global__ void zero_int_kernel(int* __restrict__ p, int n) {
  int i = blockIdx.x * blockDim.x + threadIdx.x;
  if (i < n) p[i] = 0;
}

__global__ void degree_kernel(const int* __restrict__ dst, int* __restrict__ deg, int E) {
  int e = blockIdx.x * blockDim.x + threadIdx.x;
  if (e < E) atomicAdd(&deg[dst[e]], 1);
}

// ---------------- parallel 3-phase exclusive scan (N ~ 50K, 256/block) ----
__global__ __launch_bounds__(256) void scan1_kernel(const int* __restrict__ deg,
                                                    int* __restrict__ local,
                                                    int* __restrict__ bsum, int n) {
  int t = threadIdx.x, i = blockIdx.x * 256 + t;
  int lane = t & 63, wid = t >> 6;
  __shared__ int ws[4];
  int v = (i < n) ? deg[i] : 0;
  int sc = v;
#pragma unroll
  for (int off = 1; off < 64; off <<= 1) {
    int u = __shfl_up(sc, off, 64);
    if (lane >= off) sc += u;
  }
  if (lane == 63) ws[wid] = sc;
  __syncthreads();
  int add = 0;
#pragma unroll
  for (int w = 0; w < 4; ++w) add += (w < wid) ? ws[w] : 0;
  if (i < n) local[i] = add + sc - v;
  if (t == 0) bsum[blockIdx.x] = ws[0] + ws[1] + ws[2] + ws[3];
}

__global__ __launch_bounds__(256) void scan2_kernel(int* __restrict__ bsum, int nb) {
  int t = threadIdx.x;
  int lane = t & 63, wid = t >> 6;
  __shared__ int ws[4];
  int v = (t < nb) ? bsum[t] : 0;
  int sc = v;
#pragma unroll
  for (int off = 1; off < 64; off <<= 1) {
    int u = __shfl_up(sc, off, 64);
    if (lane >= off) sc += u;
  }
  if (lane == 63) ws[wid] = sc;
  __syncthreads();
  int add = 0;
#pragma unroll
  for (int w = 0; w < 4; ++w) add += (w < wid) ? ws[w] : 0;
  if (t < nb) bsum[t] = add + sc - v;
}

__global__ __launch_bounds__(256) void scan3_kernel(const int* __restrict__ deg,
                                                    const int* __restrict__ local,
                                                    const int* __restrict__ bsum,
                                                    int* __restrict__ row_start,
                                                    int* __restrict__ cursor,
                                                    float* __restrict__ inv_deg, int n, int E) {
  int i = blockIdx.x * 256 + threadIdx.x;
  if (i < n) {
    int rs = local[i] + bsum[blockIdx.x];
    row_start[i] = rs;
    cursor[i] = rs;
    inv_deg[i] = 1.0f / fmaxf((float)deg[i], 1.0f);
  }
  if (i == 0) row_start[n] = E;
}

__global__ void fill_kernel(const int* __restrict__ src, const int* __restrict__ dst,
                            int* cursor, int* __restrict__ col, int E) {
  int e = blockIdx.x * blockDim.x + threadIdx.x;
  if (e < E) {
    int d = dst[e];
    int p = atomicAdd(&cursor[d], 1);
    col[p] = src[e];
  }
}

// ------------------------------------------------ fp32 -> fp16 row convert
// rows of 128 cols; thread handles 8 cols. out row pitch = 128 halves (256B).
__global__ __launch_bounds__(256) void to_f16_kernel(const float* __restrict__ in, int ld,
                                                     unsigned short* __restrict__ out, int nrows) {
  int idx = blockIdx.x * 256 + threadIdx.x;
  int r = idx >> 4, cc = (idx & 15) * 8;
  if (r >= nrows) return;
  const float* p = in + (size_t)r * ld + cc;
  float4 a = *reinterpret_cast<const float4*>(p);
  float4 b = *reinterpret_cast<const float4*>(p + 4);
  __half2 h0 = __floats2half2_rn(a.x, a.y);
  __half2 h1 = __floats2half2_rn(a.z, a.w);
  __half2 h2 = __floats2half2_rn(b.x, b.y);
  __half2 h3 = __floats2half2_rn(b.z, b.w);
  uint4 o;
  o.x = *reinterpret_cast<unsigned*>(&h0);
  o.y = *reinterpret_cast<unsigned*>(&h1);
  o.z = *reinterpret_cast<unsigned*>(&h2);
  o.w = *reinterpret_cast<unsigned*>(&h3);
  *reinterpret_cast<uint4*>(out + (size_t)r * DD + cc) = o;
}

// -------------------------------------------------- weight prep (bf16 split)
__global__ __launch_bounds__(256) void prep_layer_w(const float* __restrict__ Wl,
                                                    const float* __restrict__ Wr,
                                                    bf16x8* __restrict__ f) {
  int idx = blockIdx.x * 256 + threadIdx.x;  // [0, 12288)
  int lane = idx & 63;
  int ksnt = (idx >> 6) & 31;
  int mat = (idx >> 11) & 1;
  int layer = idx >> 12;
  int ks = ksnt >> 3, nt = ksnt & 7;
  int nn = nt * 16 + (lane & 15);
  int k0 = ks * 32 + (lane >> 4) * 8;
  const float* W = (mat ? Wr : Wl) + (size_t)layer * DD * DD;
  float v[8];
#pragma unroll
  for (int j = 0; j < 8; ++j) v[j] = W[(size_t)(k0 + j) * DD + nn];
  bf16x8 hi, lo;
  split8(v, hi, lo);
  size_t base = (size_t)((layer * 2 + mat) * 2) * 2048 + (size_t)ksnt * 64 + lane;
  f[base] = hi;
  f[base + 2048] = lo;
}

__global__ __launch_bounds__(256) void prep_cls_w(const float* __restrict__ Wc1,
                                                  bf16x8* __restrict__ f) {
  int idx = blockIdx.x * 256 + threadIdx.x;  // [0, 3072)
  if (idx >= 3072) return;
  int lane = idx & 63;
  int ksnt = idx >> 6;
  int ks = ksnt >> 2, nt = ksnt & 3;
  int nn = nt * 16 + (lane & 15);
  int k0 = ks * 32 + (lane >> 4) * 8;
  float v[8];
#pragma unroll
  for (int j = 0; j < 8; ++j) v[j] = Wc1[(size_t)(k0 + j) * 64 + nn];
  bf16x8 hi, lo;
  split8(v, hi, lo);
  f[idx] = hi;
  f[idx + 3072] = lo;
}

// ------------------------------------------------------------- aggregation
// fp16 gather: wave per node; 4 edges in flight (quad q = lane>>4), each lane
// reads 16B (8 halves) of its quad's edge row -> one 1KB wave load per 4 edges.
// fp32 accumulate; cross-quad shfl_xor reduction; lanes 0-15 write the row.
__global__ __launch_bounds__(256) void agg16_kernel(const unsigned short* __restrict__ h16,
                                                    const int* __restrict__ row_start,
                                                    const int* __restrict__ col,
                                                    const float* __restrict__ inv_deg,
                                                    float* __restrict__ agg, int n) {
  int wib = threadIdx.x >> 6;
  int lane = threadIdx.x & 63;
  int node = blockIdx.x * 4 + wib;
  if (node >= n) return;
  int beg = row_start[node];
  int end = row_start[node + 1];
  int q = lane >> 4, l15 = lane & 15;
  float acc[8];
#pragma unroll
  for (int k = 0; k < 8; ++k) acc[k] = 0.f;

  for (int j0 = beg; j0 < end; j0 += 64) {
    int cnt = min(64, end - j0);
    int cidx = col[j0 + min(lane, cnt - 1)];
    for (int j = 0; j < cnt; j += 4) {
      int e = j + q;
      int s = __shfl(cidx, e < cnt ? e : 0);
      if (e < cnt) {
        uint4 raw = *reinterpret_cast<const uint4*>(h16 + (size_t)s * DD + l15 * 8);
        __half2 v0 = *reinterpret_cast<__half2*>(&raw.x);
        __half2 v1 = *reinterpret_cast<__half2*>(&raw.y);
        __half2 v2 = *reinterpret_cast<__half2*>(&raw.z);
        __half2 v3 = *reinterpret_cast<__half2*>(&raw.w);
        float2 f;
        f = __half22float2(v0); acc[0] += f.x; acc[1] += f.y;
        f = __half22float2(v1); acc[2] += f.x; acc[3] += f.y;
        f = __half22float2(v2); acc[4] += f.x; acc[5] += f.y;
        f = __half22float2(v3); acc[6] += f.x; acc[7] += f.y;
      }
    }
  }
#pragma unroll
  for (int m = 16; m <= 32; m <<= 1) {
#pragma unroll
    for (int k = 0; k < 8; ++k) acc[k] += __shfl_xor(acc[k], m);
  }
  if (lane < 16) {
    float w = inv_deg[node];
    float4 o0 = {acc[0] * w, acc[1] * w, acc[2] * w, acc[3] * w};
    float4 o1 = {acc[4] * w, acc[5] * w, acc[6] * w, acc[7] * w};
    float* op = agg + (size_t)node * DD + l15 * 8;
    *reinterpret_cast<float4*>(op) = o0;
    *reinterpret_cast<float4*>(op + 4) = o1;
  }
}

// ---------------------------------------- MFMA layer GEMM + BN + ReLU (no LDS)
__global__ __launch_bounds__(256) void layer_gemm_mfma(
    const float* __restrict__ hin, int ldh, const float* __restrict__ agg,
    const bf16x8* __restrict__ Blh_g, const bf16x8* __restrict__ Bll_g,
    const bf16x8* __restrict__ Brh_g, const bf16x8* __restrict__ Brl_g,
    const float* __restrict__ bl, const float* __restrict__ gamma,
    const float* __restrict__ beta, const float* __restrict__ rmean,
    const float* __restrict__ rvar, float* __restrict__ out, int ldo, int n) {
  int t = threadIdx.x;
  int w = t >> 6, lane = t & 63;
  int lane16 = lane & 15, quad = lane >> 4;
  int row0 = blockIdx.x * 64;
  int m = row0 + w * 16 + lane16;
  bool valid = m < n;
  size_t mrow = (size_t)(valid ? m : 0);
  const float* ap = agg + mrow * DD + quad * 8;
  const float* hp = hin + mrow * (size_t)ldh + quad * 8;

  bf16x8 Ah[4], Al[4], Hh[4], Hl[4];
#pragma unroll
  for (int ks = 0; ks < 4; ++ks) {
    float a8[8] __attribute__((aligned(16)));
    float h8[8] __attribute__((aligned(16)));
    if (valid) {
      *reinterpret_cast<float4*>(a8) = *reinterpret_cast<const float4*>(ap + ks * 32);
      *reinterpret_cast<float4*>(a8 + 4) = *reinterpret_cast<const float4*>(ap + ks * 32 + 4);
      *reinterpret_cast<float4*>(h8) = *reinterpret_cast<const float4*>(hp + ks * 32);
      *reinterpret_cast<float4*>(h8 + 4) = *reinterpret_cast<const float4*>(hp + ks * 32 + 4);
    } else {
#pragma unroll
      for (int j = 0; j < 8; ++j) { a8[j] = 0.f; h8[j] = 0.f; }
    }
    split8(a8, Ah[ks], Al[ks]);
    split8(h8, Hh[ks], Hl[ks]);
  }

  f32x4 acc[8];
#pragma unroll
  for (int nt = 0; nt < 8; ++nt) acc[nt] = (f32x4){0.f, 0.f, 0.f, 0.f};

#pragma unroll
  for (int ks = 0; ks < 4; ++ks) {
    int fb = ks * 8 * 64 + lane;
    bf16x8 B0[8], B1[8];
#pragma unroll
    for (int nt = 0; nt < 8; ++nt) B0[nt] = Blh_g[fb + nt * 64];
#pragma unroll
    for (int nt = 0; nt < 8; ++nt) acc[nt] = MFMA(Ah[ks], B0[nt], acc[nt]);
#pragma unroll
    for (int nt = 0; nt < 8; ++nt) B1[nt] = Bll_g[fb + nt * 64];
#pragma unroll
    for (int nt = 0; nt < 8; ++nt) acc[nt] = MFMA(Al[ks], B0[nt], acc[nt]);
#pragma unroll
    for (int nt = 0; nt < 8; ++nt) acc[nt] = MFMA(Ah[ks], B1[nt], acc[nt]);
#pragma unroll
    for (int nt = 0; nt < 8; ++nt) B0[nt] = Brh_g[fb + nt * 64];
#pragma unroll
    for (int nt = 0; nt < 8; ++nt) acc[nt] = MFMA(Hh[ks], B0[nt], acc[nt]);
#pragma unroll
    for (int nt = 0; nt < 8; ++nt) B1[nt] = Brl_g[fb + nt * 64];
#pragma unroll
    for (int nt = 0; nt < 8; ++nt) acc[nt] = MFMA(Hl[ks], B0[nt], acc[nt]);
#pragma unroll
    for (int nt = 0; nt < 8; ++nt) acc[nt] = MFMA(Hh[ks], B1[nt], acc[nt]);
  }

#pragma unroll
  for (int nt = 0; nt < 8; ++nt) {
    int c = nt * 16 + lane16;
    float sc = gamma[c] * rsqrtf(rvar[c] + EPSV);
    float sh = (bl[c] - rmean[c]) * sc + beta[c];
#pragma unroll
    for (int r = 0; r < 4; ++r) {
      int orow = row0 + w * 16 + quad * 4 + r;
      if (orow < n)
        out[(size_t)orow * ldo + c] = fmaxf(fmaf(acc[nt][r], sc, sh), 0.f);
    }
  }
}

// ------------------------------------------------------ MFMA classifier
__global__ __launch_bounds__(256) void classifier_mfma(
    const float* __restrict__ jk, const bf16x8* __restrict__ Bh_g,
    const bf16x8* __restrict__ Bl_g, const float* __restrict__ bc1,
    const float* __restrict__ Wc2, const float* __restrict__ bc2,
    float* __restrict__ out, int n) {
  __shared__ float sZ[64][65];
  int t = threadIdx.x;
  int w = t >> 6, lane = t & 63;
  int lane16 = lane & 15, quad = lane >> 4;
  int row0 = blockIdx.x * 64;
  int m = row0 + w * 16 + lane16;
  bool valid = m < n;
  const float* jp = jk + (size_t)(valid ? m : 0) * (3 * DD) + quad * 8;

  f32x4 acc[4];
#pragma unroll
  for (int nt = 0; nt < 4; ++nt) acc[nt] = (f32x4){0.f, 0.f, 0.f, 0.f};

#pragma unroll
  for (int ks = 0; ks < 12; ++ks) {
    float a8[8] __attribute__((aligned(16)));
    if (valid) {
      *reinterpret_cast<float4*>(a8) = *reinterpret_cast<const float4*>(jp + ks * 32);
      *reinterpret_cast<float4*>(a8 + 4) = *reinterpret_cast<const float4*>(jp + ks * 32 + 4);
    } else {
#pragma unroll
      for (int j = 0; j < 8; ++j) a8[j] = 0.f;
    }
    bf16x8 Jh, Jl;
    split8(a8, Jh, Jl);
    int fb = ks * 4 * 64 + lane;
    bf16x8 B0[4], B1[4];
#pragma unroll
    for (int nt = 0; nt < 4; ++nt) B0[nt] = Bh_g[fb + nt * 64];
#pragma unroll
    for (int nt = 0; nt < 4; ++nt) acc[nt] = MFMA(Jh, B0[nt], acc[nt]);
#pragma unroll
    for (int nt = 0; nt < 4; ++nt) B1[nt] = Bl_g[fb + nt * 64];
#pragma unroll
    for (int nt = 0; nt < 4; ++nt) acc[nt] = MFMA(Jl, B0[nt], acc[nt]);
#pragma unroll
    for (int nt = 0; nt < 4; ++nt) acc[nt] = MFMA(Jh, B1[nt], acc[nt]);
  }

#pragma unroll
  for (int nt = 0; nt < 4; ++nt) {
    int c = nt * 16 + lane16;
    float b1 = bc1[c];
#pragma unroll
    for (int r = 0; r < 4; ++r)
      sZ[w * 16 + quad * 4 + r][c] = fmaxf(acc[nt][r] + b1, 0.f);
  }
  __syncthreads();

  if (t < 128) {
    int r = t >> 1, j = t & 1;
    int gr = row0 + r;
    if (gr < n) {
      float s = bc2[j];
#pragma unroll
      for (int c = 0; c < 64; ++c) s = fmaf(sZ[r][c], Wc2[c * 2 + j], s);
      out[(size_t)gr * 2 + j] = s;
    }
  }
}

// ----------------------------------------------------------------- launch

extern "C" void kernel_launch(void* const* d_in, const int* in_sizes, int n_in,
                              void* d_out, int out_size, void* d_ws, size_t ws_size,
                              hipStream_t stream) {
  const float* x = (const float*)d_in[0];
  const int* ei = (const int*)d_in[1];
  const float* Wl = (const float*)d_in[2];
  const float* bl = (const float*)d_in[3];
  const float* Wr = (const float*)d_in[4];
  const float* gamma = (const float*)d_in[5];
  const float* beta = (const float*)d_in[6];
  const float* rmean = (const float*)d_in[7];
  const float* rvar = (const float*)d_in[8];
  const float* Wc1 = (const float*)d_in[9];
  const float* bc1 = (const float*)d_in[10];
  const float* Wc2 = (const float*)d_in[11];
  const float* bc2 = (const float*)d_in[12];
  float* out = (float*)d_out;

  const int N = in_sizes[0] / DD;
  const int E = in_sizes[1] / 2;
  const int* src = ei;
  const int* dst = ei + E;

  auto align = [](size_t v) { return (v + 255) & ~(size_t)255; };
  char* ws = (char*)d_ws;
  size_t off = 0;
  int* deg = (int*)(ws + off);      off = align(off + sizeof(int) * (size_t)N);
  int* row_start = (int*)(ws + off); off = align(off + sizeof(int) * (size_t)(N + 1));
  int* cursor = (int*)(ws + off);   off = align(off + sizeof(int) * (size_t)N);
  int* col = (int*)(ws + off);      off = align(off + sizeof(int) * (size_t)E);
  float* inv_deg = (float*)(ws + off); off = align(off + sizeof(float) * (size_t)N);
  int* slocal = (int*)(ws + off);   off = align(off + sizeof(int) * (size_t)N);
  int* bsum = (int*)(ws + off);     off = align(off + sizeof(int) * 256);
  float* agg = (float*)(ws + off);  off = align(off + sizeof(float) * (size_t)N * DD);
  float* jk = (float*)(ws + off);   off = align(off + sizeof(float) * (size_t)N * 3 * DD);
  unsigned short* h16 = (unsigned short*)(ws + off); off = align(off + sizeof(short) * (size_t)N * DD);
  bf16x8* wf = (bf16x8*)(ws + off); off = align(off + (size_t)16 * 3 * 2 * 2 * 2048);
  bf16x8* wcf = (bf16x8*)(ws + off); off = align(off + (size_t)16 * 2 * 3072);

  const int nb = (N + 255) / 256;
  zero_int_kernel<<<(N + 255) / 256, 256, 0, stream>>>(deg, N);
  degree_kernel<<<(E + 255) / 256, 256, 0, stream>>>(dst, deg, E);
  scan1_kernel<<<nb, 256, 0, stream>>>(deg, slocal, bsum, N);
  scan2_kernel<<<1, 256, 0, stream>>>(bsum, nb);
  scan3_kernel<<<nb, 256, 0, stream>>>(deg, slocal, bsum, row_start, cursor, inv_deg, N, E);
  fill_kernel<<<(E + 255) / 256, 256, 0, stream>>>(src, dst, cursor, col, E);
  prep_layer_w<<<48, 256, 0, stream>>>(Wl, Wr, wf);
  prep_cls_w<<<12, 256, 0, stream>>>(Wc1, wcf);
  to_f16_kernel<<<(N * 16 + 255) / 256, 256, 0, stream>>>(x, DD, h16, N);

  int nTiles = (N + 63) / 64;
  for (int i = 0; i < 3; ++i) {
    const float* hin = (i == 0) ? x : (jk + (size_t)(i - 1) * DD);
    int ldh = (i == 0) ? DD : 3 * DD;
    agg16_kernel<<<(N + 3) / 4, 256, 0, stream>>>(h16, row_start, col, inv_deg, agg, N);
    bf16x8* Wlf = wf + (size_t)(i * 2 + 0) * 2 * 2048;
    bf16x8* Wrf = wf + (size_t)(i * 2 + 1) * 2 * 2048;
    layer_gemm_mfma<<<nTiles, 256, 0, stream>>>(
        hin, ldh, agg, Wlf, Wlf + 2048, Wrf, Wrf + 2048,
        bl + (size_t)i * DD, gamma + (size_t)i * DD, beta + (size_t)i * DD,
        rmean + (size_t)i * DD, rvar + (size_t)i * DD, jk + (size_t)i * DD, 3 * DD, N);
    if (i < 2)
      to_f16_kernel<<<(N * 16 + 255) / 256, 256, 0, stream>>>(jk + (size_t)i * DD, 3 * DD, h16, N);
  }
  classifier_mfma<<<nTiles, 256, 0, stream>>>(jk, wcf, wcf + 3072, bc1, Wc2, bc2, out, N);
}

// Round 5
// 405.675 us; speedup vs baseline: 2.0825x; 1.0288x over previous
//
#include <hip/hip_runtime.h>
#include <hip/hip_fp16.h>
#include <cstdint>
#include <cstddef>

#define DD 128
#define EPSV 1e-5f

typedef __attribute__((ext_vector_type(8))) short bf16x8;
typedef __attribute__((ext_vector_type(4))) float f32x4;
#define MFMA(a, b, c) __builtin_amdgcn_mfma_f32_16x16x32_bf16(a, b, c, 0, 0, 0)

__device__ inline unsigned short f2bf_rne(float f) {
  unsigned u = __float_as_uint(f);
  unsigned r = u + 0x7fffu + ((u >> 16) & 1u);
  return (unsigned short)(r >> 16);
}

__device__ inline void split8(const float* s, bf16x8& hi, bf16x8& lo) {
#pragma unroll
  for (int j = 0; j < 8; ++j) {
    float f = s[j];
    unsigned short h = f2bf_rne(f);
    float fh = __uint_as_float((unsigned)h << 16);
    hi[j] = (short)h;
    lo[j] = (short)f2bf_rne(f - fh);
  }
}

// ---------------------------------------------------------------- utilities

__global__ void zero_int_kernel(int* __restrict__ p, int n) {
  int i = blockIdx.x * blockDim.x + threadIdx.x;
  if (i < n) p[i] = 0;
}

__global__ void degree_kernel(const int* __restrict__ dst, int* __restrict__ deg, int E) {
  int e = blockIdx.x * blockDim.x + threadIdx.x;
  if (e < E) atomicAdd(&deg[dst[e]], 1);
}

// ---------------- parallel 3-phase exclusive scan ----
__global__ __launch_bounds__(256) void scan1_kernel(const int* __restrict__ deg,
                                                    int* __restrict__ local,
                                                    int* __restrict__ bsum, int n) {
  int t = threadIdx.x, i = blockIdx.x * 256 + t;
  int lane = t & 63, wid = t >> 6;
  __shared__ int ws[4];
  int v = (i < n) ? deg[i] : 0;
  int sc = v;
#pragma unroll
  for (int off = 1; off < 64; off <<= 1) {
    int u = __shfl_up(sc, off, 64);
    if (lane >= off) sc += u;
  }
  if (lane == 63) ws[wid] = sc;
  __syncthreads();
  int add = 0;
#pragma unroll
  for (int w = 0; w < 4; ++w) add += (w < wid) ? ws[w] : 0;
  if (i < n) local[i] = add + sc - v;
  if (t == 0) bsum[blockIdx.x] = ws[0] + ws[1] + ws[2] + ws[3];
}

__global__ __launch_bounds__(256) void scan2_kernel(int* __restrict__ bsum, int nb) {
  int t = threadIdx.x;
  int lane = t & 63, wid = t >> 6;
  __shared__ int ws[4];
  int v = (t < nb) ? bsum[t] : 0;
  int sc = v;
#pragma unroll
  for (int off = 1; off < 64; off <<= 1) {
    int u = __shfl_up(sc, off, 64);
    if (lane >= off) sc += u;
  }
  if (lane == 63) ws[wid] = sc;
  __syncthreads();
  int add = 0;
#pragma unroll
  for (int w = 0; w < 4; ++w) add += (w < wid) ? ws[w] : 0;
  if (t < nb) bsum[t] = add + sc - v;
}

__global__ __launch_bounds__(256) void scan3_kernel(const int* __restrict__ deg,
                                                    const int* __restrict__ local,
                                                    const int* __restrict__ bsum,
                                                    int* __restrict__ row_start,
                                                    int* __restrict__ cursor,
                                                    float* __restrict__ inv_deg, int n, int E) {
  int i = blockIdx.x * 256 + threadIdx.x;
  if (i < n) {
    int rs = local[i] + bsum[blockIdx.x];
    row_start[i] = rs;
    cursor[i] = rs;
    inv_deg[i] = 1.0f / fmaxf((float)deg[i], 1.0f);
  }
  if (i == 0) row_start[n] = E;
}

// ------------------------------------------------------- XCD-binned CSR fill
// col-line write merging requires all writers of a 64B col line to share one
// XCD's L2. Bin = (dst>>5)&7: 32-node groups own 2KB contiguous CSR regions.
// Block b (xcd = b&7, chunk = b>>3) scans chunk and takes only its bin's
// edges; relies on round-robin block->XCD dispatch for SPEED only --
// every edge is processed exactly once regardless of the actual mapping.
#define FILL_CH 4096
__global__ __launch_bounds__(256) void fill_binned_kernel(const int* __restrict__ src,
                                                          const int* __restrict__ dst,
                                                          int* cursor, int* __restrict__ col,
                                                          int E) {
  int xcd = blockIdx.x & 7;
  int base = (blockIdx.x >> 3) * FILL_CH + threadIdx.x;
#pragma unroll
  for (int it = 0; it < FILL_CH / 256; ++it) {
    int e = base + it * 256;
    if (e < E) {
      int d = dst[e];
      if (((d >> 5) & 7) == xcd) {
        int p = atomicAdd(&cursor[d], 1);
        col[p] = src[e];
      }
    }
  }
}

// ------------------------------------------------ fp32 -> fp16 row convert
__global__ __launch_bounds__(256) void to_f16_kernel(const float* __restrict__ in, int ld,
                                                     unsigned short* __restrict__ out, int nrows) {
  int idx = blockIdx.x * 256 + threadIdx.x;
  int r = idx >> 4, cc = (idx & 15) * 8;
  if (r >= nrows) return;
  const float* p = in + (size_t)r * ld + cc;
  float4 a = *reinterpret_cast<const float4*>(p);
  float4 b = *reinterpret_cast<const float4*>(p + 4);
  __half2 h0 = __floats2half2_rn(a.x, a.y);
  __half2 h1 = __floats2half2_rn(a.z, a.w);
  __half2 h2 = __floats2half2_rn(b.x, b.y);
  __half2 h3 = __floats2half2_rn(b.z, b.w);
  uint4 o;
  o.x = *reinterpret_cast<unsigned*>(&h0);
  o.y = *reinterpret_cast<unsigned*>(&h1);
  o.z = *reinterpret_cast<unsigned*>(&h2);
  o.w = *reinterpret_cast<unsigned*>(&h3);
  *reinterpret_cast<uint4*>(out + (size_t)r * DD + cc) = o;
}

// -------------------------------------------------- weight prep (bf16 split)
__global__ __launch_bounds__(256) void prep_layer_w(const float* __restrict__ Wl,
                                                    const float* __restrict__ Wr,
                                                    bf16x8* __restrict__ f) {
  int idx = blockIdx.x * 256 + threadIdx.x;  // [0, 12288)
  int lane = idx & 63;
  int ksnt = (idx >> 6) & 31;
  int mat = (idx >> 11) & 1;
  int layer = idx >> 12;
  int ks = ksnt >> 3, nt = ksnt & 7;
  int nn = nt * 16 + (lane & 15);
  int k0 = ks * 32 + (lane >> 4) * 8;
  const float* W = (mat ? Wr : Wl) + (size_t)layer * DD * DD;
  float v[8];
#pragma unroll
  for (int j = 0; j < 8; ++j) v[j] = W[(size_t)(k0 + j) * DD + nn];
  bf16x8 hi, lo;
  split8(v, hi, lo);
  size_t base = (size_t)((layer * 2 + mat) * 2) * 2048 + (size_t)ksnt * 64 + lane;
  f[base] = hi;
  f[base + 2048] = lo;
}

__global__ __launch_bounds__(256) void prep_cls_w(const float* __restrict__ Wc1,
                                                  bf16x8* __restrict__ f) {
  int idx = blockIdx.x * 256 + threadIdx.x;  // [0, 3072)
  if (idx >= 3072) return;
  int lane = idx & 63;
  int ksnt = idx >> 6;
  int ks = ksnt >> 2, nt = ksnt & 3;
  int nn = nt * 16 + (lane & 15);
  int k0 = ks * 32 + (lane >> 4) * 8;
  float v[8];
#pragma unroll
  for (int j = 0; j < 8; ++j) v[j] = Wc1[(size_t)(k0 + j) * 64 + nn];
  bf16x8 hi, lo;
  split8(v, hi, lo);
  f[idx] = hi;
  f[idx + 3072] = lo;
}

// ------------------------------------------------------------- aggregation
__global__ __launch_bounds__(256) void agg16_kernel(const unsigned short* __restrict__ h16,
                                                    const int* __restrict__ row_start,
                                                    const int* __restrict__ col,
                                                    const float* __restrict__ inv_deg,
                                                    float* __restrict__ agg, int n) {
  int wib = threadIdx.x >> 6;
  int lane = threadIdx.x & 63;
  int node = blockIdx.x * 4 + wib;
  if (node >= n) return;
  int beg = row_start[node];
  int end = row_start[node + 1];
  int q = lane >> 4, l15 = lane & 15;
  float acc[8];
#pragma unroll
  for (int k = 0; k < 8; ++k) acc[k] = 0.f;

  for (int j0 = beg; j0 < end; j0 += 64) {
    int cnt = min(64, end - j0);
    int cidx = col[j0 + min(lane, cnt - 1)];
    for (int j = 0; j < cnt; j += 4) {
      int e = j + q;
      int s = __shfl(cidx, e < cnt ? e : 0);
      if (e < cnt) {
        uint4 raw = *reinterpret_cast<const uint4*>(h16 + (size_t)s * DD + l15 * 8);
        __half2 v0 = *reinterpret_cast<__half2*>(&raw.x);
        __half2 v1 = *reinterpret_cast<__half2*>(&raw.y);
        __half2 v2 = *reinterpret_cast<__half2*>(&raw.z);
        __half2 v3 = *reinterpret_cast<__half2*>(&raw.w);
        float2 f;
        f = __half22float2(v0); acc[0] += f.x; acc[1] += f.y;
        f = __half22float2(v1); acc[2] += f.x; acc[3] += f.y;
        f = __half22float2(v2); acc[4] += f.x; acc[5] += f.y;
        f = __half22float2(v3); acc[6] += f.x; acc[7] += f.y;
      }
    }
  }
#pragma unroll
  for (int m = 16; m <= 32; m <<= 1) {
#pragma unroll
    for (int k = 0; k < 8; ++k) acc[k] += __shfl_xor(acc[k], m);
  }
  if (lane < 16) {
    float w = inv_deg[node];
    float4 o0 = {acc[0] * w, acc[1] * w, acc[2] * w, acc[3] * w};
    float4 o1 = {acc[4] * w, acc[5] * w, acc[6] * w, acc[7] * w};
    float* op = agg + (size_t)node * DD + l15 * 8;
    *reinterpret_cast<float4*>(op) = o0;
    *reinterpret_cast<float4*>(op + 4) = o1;
  }
}

// ---------------------------------------- MFMA layer GEMM + BN + ReLU (no LDS)
// Epilogue optionally emits the fp16 copy of the output row (h16out != null),
// replacing the standalone to_f16 pass for layers 0,1.
__global__ __launch_bounds__(256) void layer_gemm_mfma(
    const float* __restrict__ hin, int ldh, const float* __restrict__ agg,
    const bf16x8* __restrict__ Blh_g, const bf16x8* __restrict__ Bll_g,
    const bf16x8* __restrict__ Brh_g, const bf16x8* __restrict__ Brl_g,
    const float* __restrict__ bl, const float* __restrict__ gamma,
    const float* __restrict__ beta, const float* __restrict__ rmean,
    const float* __restrict__ rvar, float* __restrict__ out, int ldo,
    unsigned short* __restrict__ h16out, int n) {
  int t = threadIdx.x;
  int w = t >> 6, lane = t & 63;
  int lane16 = lane & 15, quad = lane >> 4;
  int row0 = blockIdx.x * 64;
  int m = row0 + w * 16 + lane16;
  bool valid = m < n;
  size_t mrow = (size_t)(valid ? m : 0);
  const float* ap = agg + mrow * DD + quad * 8;
  const float* hp = hin + mrow * (size_t)ldh + quad * 8;

  bf16x8 Ah[4], Al[4], Hh[4], Hl[4];
#pragma unroll
  for (int ks = 0; ks < 4; ++ks) {
    float a8[8] __attribute__((aligned(16)));
    float h8[8] __attribute__((aligned(16)));
    if (valid) {
      *reinterpret_cast<float4*>(a8) = *reinterpret_cast<const float4*>(ap + ks * 32);
      *reinterpret_cast<float4*>(a8 + 4) = *reinterpret_cast<const float4*>(ap + ks * 32 + 4);
      *reinterpret_cast<float4*>(h8) = *reinterpret_cast<const float4*>(hp + ks * 32);
      *reinterpret_cast<float4*>(h8 + 4) = *reinterpret_cast<const float4*>(hp + ks * 32 + 4);
    } else {
#pragma unroll
      for (int j = 0; j < 8; ++j) { a8[j] = 0.f; h8[j] = 0.f; }
    }
    split8(a8, Ah[ks], Al[ks]);
    split8(h8, Hh[ks], Hl[ks]);
  }

  f32x4 acc[8];
#pragma unroll
  for (int nt = 0; nt < 8; ++nt) acc[nt] = (f32x4){0.f, 0.f, 0.f, 0.f};

#pragma unroll
  for (int ks = 0; ks < 4; ++ks) {
    int fb = ks * 8 * 64 + lane;
    bf16x8 B0[8], B1[8];
#pragma unroll
    for (int nt = 0; nt < 8; ++nt) B0[nt] = Blh_g[fb + nt * 64];
#pragma unroll
    for (int nt = 0; nt < 8; ++nt) acc[nt] = MFMA(Ah[ks], B0[nt], acc[nt]);
#pragma unroll
    for (int nt = 0; nt < 8; ++nt) B1[nt] = Bll_g[fb + nt * 64];
#pragma unroll
    for (int nt = 0; nt < 8; ++nt) acc[nt] = MFMA(Al[ks], B0[nt], acc[nt]);
#pragma unroll
    for (int nt = 0; nt < 8; ++nt) acc[nt] = MFMA(Ah[ks], B1[nt], acc[nt]);
#pragma unroll
    for (int nt = 0; nt < 8; ++nt) B0[nt] = Brh_g[fb + nt * 64];
#pragma unroll
    for (int nt = 0; nt < 8; ++nt) acc[nt] = MFMA(Hh[ks], B0[nt], acc[nt]);
#pragma unroll
    for (int nt = 0; nt < 8; ++nt) B1[nt] = Brl_g[fb + nt * 64];
#pragma unroll
    for (int nt = 0; nt < 8; ++nt) acc[nt] = MFMA(Hl[ks], B0[nt], acc[nt]);
#pragma unroll
    for (int nt = 0; nt < 8; ++nt) acc[nt] = MFMA(Hh[ks], B1[nt], acc[nt]);
  }

#pragma unroll
  for (int nt = 0; nt < 8; ++nt) {
    int c = nt * 16 + lane16;
    float sc = gamma[c] * rsqrtf(rvar[c] + EPSV);
    float sh = (bl[c] - rmean[c]) * sc + beta[c];
#pragma unroll
    for (int r = 0; r < 4; ++r) {
      int orow = row0 + w * 16 + quad * 4 + r;
      if (orow < n) {
        float v = fmaxf(fmaf(acc[nt][r], sc, sh), 0.f);
        out[(size_t)orow * ldo + c] = v;
        if (h16out) {
          __half hv = __float2half_rn(v);
          h16out[(size_t)orow * DD + c] = *reinterpret_cast<unsigned short*>(&hv);
        }
      }
    }
  }
}

// ------------------------------------------------------ MFMA classifier
__global__ __launch_bounds__(256) void classifier_mfma(
    const float* __restrict__ jk, const bf16x8* __restrict__ Bh_g,
    const bf16x8* __restrict__ Bl_g, const float* __restrict__ bc1,
    const float* __restrict__ Wc2, const float* __restrict__ bc2,
    float* __restrict__ out, int n) {
  __shared__ float sZ[64][65];
  int t = threadIdx.x;
  int w = t >> 6, lane = t & 63;
  int lane16 = lane & 15, quad = lane >> 4;
  int row0 = blockIdx.x * 64;
  int m = row0 + w * 16 + lane16;
  bool valid = m < n;
  const float* jp = jk + (size_t)(valid ? m : 0) * (3 * DD) + quad * 8;

  f32x4 acc[4];
#pragma unroll
  for (int nt = 0; nt < 4; ++nt) acc[nt] = (f32x4){0.f, 0.f, 0.f, 0.f};

#pragma unroll
  for (int ks = 0; ks < 12; ++ks) {
    float a8[8] __attribute__((aligned(16)));
    if (valid) {
      *reinterpret_cast<float4*>(a8) = *reinterpret_cast<const float4*>(jp + ks * 32);
      *reinterpret_cast<float4*>(a8 + 4) = *reinterpret_cast<const float4*>(jp + ks * 32 + 4);
    } else {
#pragma unroll
      for (int j = 0; j < 8; ++j) a8[j] = 0.f;
    }
    bf16x8 Jh, Jl;
    split8(a8, Jh, Jl);
    int fb = ks * 4 * 64 + lane;
    bf16x8 B0[4], B1[4];
#pragma unroll
    for (int nt = 0; nt < 4; ++nt) B0[nt] = Bh_g[fb + nt * 64];
#pragma unroll
    for (int nt = 0; nt < 4; ++nt) acc[nt] = MFMA(Jh, B0[nt], acc[nt]);
#pragma unroll
    for (int nt = 0; nt < 4; ++nt) B1[nt] = Bl_g[fb + nt * 64];
#pragma unroll
    for (int nt = 0; nt < 4; ++nt) acc[nt] = MFMA(Jl, B0[nt], acc[nt]);
#pragma unroll
    for (int nt = 0; nt < 4; ++nt) acc[nt] = MFMA(Jh, B1[nt], acc[nt]);
  }

#pragma unroll
  for (int nt = 0; nt < 4; ++nt) {
    int c = nt * 16 + lane16;
    float b1 = bc1[c];
#pragma unroll
    for (int r = 0; r < 4; ++r)
      sZ[w * 16 + quad * 4 + r][c] = fmaxf(acc[nt][r] + b1, 0.f);
  }
  __syncthreads();

  if (t < 128) {
    int r = t >> 1, j = t & 1;
    int gr = row0 + r;
    if (gr < n) {
      float s = bc2[j];
#pragma unroll
      for (int c = 0; c < 64; ++c) s = fmaf(sZ[r][c], Wc2[c * 2 + j], s);
      out[(size_t)gr * 2 + j] = s;
    }
  }
}

// ----------------------------------------------------------------- launch

extern "C" void kernel_launch(void* const* d_in, const int* in_sizes, int n_in,
                              void* d_out, int out_size, void* d_ws, size_t ws_size,
                              hipStream_t stream) {
  const float* x = (const float*)d_in[0];
  const int* ei = (const int*)d_in[1];
  const float* Wl = (const float*)d_in[2];
  const float* bl = (const float*)d_in[3];
  const float* Wr = (const float*)d_in[4];
  const float* gamma = (const float*)d_in[5];
  const float* beta = (const float*)d_in[6];
  const float* rmean = (const float*)d_in[7];
  const float* rvar = (const float*)d_in[8];
  const float* Wc1 = (const float*)d_in[9];
  const float* bc1 = (const float*)d_in[10];
  const float* Wc2 = (const float*)d_in[11];
  const float* bc2 = (const float*)d_in[12];
  float* out = (float*)d_out;

  const int N = in_sizes[0] / DD;
  const int E = in_sizes[1] / 2;
  const int* src = ei;
  const int* dst = ei + E;

  auto align = [](size_t v) { return (v + 255) & ~(size_t)255; };
  char* ws = (char*)d_ws;
  size_t off = 0;
  int* deg = (int*)(ws + off);      off = align(off + sizeof(int) * (size_t)N);
  int* row_start = (int*)(ws + off); off = align(off + sizeof(int) * (size_t)(N + 1));
  int* cursor = (int*)(ws + off);   off = align(off + sizeof(int) * (size_t)N);
  int* col = (int*)(ws + off);      off = align(off + sizeof(int) * (size_t)E);
  float* inv_deg = (float*)(ws + off); off = align(off + sizeof(float) * (size_t)N);
  int* slocal = (int*)(ws + off);   off = align(off + sizeof(int) * (size_t)N);
  int* bsum = (int*)(ws + off);     off = align(off + sizeof(int) * 256);
  float* agg = (float*)(ws + off);  off = align(off + sizeof(float) * (size_t)N * DD);
  float* jk = (float*)(ws + off);   off = align(off + sizeof(float) * (size_t)N * 3 * DD);
  unsigned short* h16 = (unsigned short*)(ws + off); off = align(off + sizeof(short) * (size_t)N * DD);
  bf16x8* wf = (bf16x8*)(ws + off); off = align(off + (size_t)16 * 3 * 2 * 2 * 2048);
  bf16x8* wcf = (bf16x8*)(ws + off); off = align(off + (size_t)16 * 2 * 3072);

  const int nb = (N + 255) / 256;
  zero_int_kernel<<<(N + 255) / 256, 256, 0, stream>>>(deg, N);
  degree_kernel<<<(E + 255) / 256, 256, 0, stream>>>(dst, deg, E);
  scan1_kernel<<<nb, 256, 0, stream>>>(deg, slocal, bsum, N);
  scan2_kernel<<<1, 256, 0, stream>>>(bsum, nb);
  scan3_kernel<<<nb, 256, 0, stream>>>(deg, slocal, bsum, row_start, cursor, inv_deg, N, E);
  {
    int nChunks = (E + FILL_CH - 1) / FILL_CH;
    fill_binned_kernel<<<nChunks * 8, 256, 0, stream>>>(src, dst, cursor, col, E);
  }
  prep_layer_w<<<48, 256, 0, stream>>>(Wl, Wr, wf);
  prep_cls_w<<<12, 256, 0, stream>>>(Wc1, wcf);
  to_f16_kernel<<<(N * 16 + 255) / 256, 256, 0, stream>>>(x, DD, h16, N);

  int nTiles = (N + 63) / 64;
  for (int i = 0; i < 3; ++i) {
    const float* hin = (i == 0) ? x : (jk + (size_t)(i - 1) * DD);
    int ldh = (i == 0) ? DD : 3 * DD;
    agg16_kernel<<<(N + 3) / 4, 256, 0, stream>>>(h16, row_start, col, inv_deg, agg, N);
    bf16x8* Wlf = wf + (size_t)(i * 2 + 0) * 2 * 2048;
    bf16x8* Wrf = wf + (size_t)(i * 2 + 1) * 2 * 2048;
    layer_gemm_mfma<<<nTiles, 256, 0, stream>>>(
        hin, ldh, agg, Wlf, Wlf + 2048, Wrf, Wrf + 2048,
        bl + (size_t)i * DD, gamma + (size_t)i * DD, beta + (size_t)i * DD,
        rmean + (size_t)i * DD, rvar + (size_t)i * DD, jk + (size_t)i * DD, 3 * DD,
        (i < 2) ? h16 : (unsigned short*)nullptr, N);
  }
  classifier_mfma<<<nTiles, 256, 0, stream>>>(jk, wcf, wcf + 3072, bc1, Wc2, bc2, out, N);
}

// Round 6
// 381.382 us; speedup vs baseline: 2.2151x; 1.0637x over previous
//
#include <hip/hip_runtime.h>
#include <hip/hip_fp16.h>
#include <cstdint>
#include <cstddef>

#define DD 128
#define JKD 384
#define EPSV 1e-5f

typedef __attribute__((ext_vector_type(8))) short bf16x8;
typedef __attribute__((ext_vector_type(4))) float f32x4;
#define MFMA(a, b, c) __builtin_amdgcn_mfma_f32_16x16x32_bf16(a, b, c, 0, 0, 0)

__device__ inline unsigned short f2bf_rne(float f) {
  unsigned u = __float_as_uint(f);
  unsigned r = u + 0x7fffu + ((u >> 16) & 1u);
  return (unsigned short)(r >> 16);
}

__device__ inline void split8(const float* s, bf16x8& hi, bf16x8& lo) {
#pragma unroll
  for (int j = 0; j < 8; ++j) {
    float f = s[j];
    unsigned short h = f2bf_rne(f);
    float fh = __uint_as_float((unsigned)h << 16);
    hi[j] = (short)h;
    lo[j] = (short)f2bf_rne(f - fh);
  }
}

// 8 halves (as uint4) -> 8 floats
__device__ inline void h8_to_f8(uint4 raw, float* out) {
  const __half2* hp = reinterpret_cast<const __half2*>(&raw);
#pragma unroll
  for (int j = 0; j < 4; ++j) {
    float2 f = __half22float2(hp[j]);
    out[2 * j] = f.x;
    out[2 * j + 1] = f.y;
  }
}

// ---------------------------------------------------------------- utilities

__global__ void zero_int_kernel(int* __restrict__ p, int n) {
  int i = blockIdx.x * blockDim.x + threadIdx.x;
  if (i < n) p[i] = 0;
}

__global__ void degree_kernel(const int* __restrict__ dst, int* __restrict__ deg, int E) {
  int e = blockIdx.x * blockDim.x + threadIdx.x;
  if (e < E) {
    int d = __builtin_nontemporal_load(dst + e);
    atomicAdd(&deg[d], 1);
  }
}

// ---------------- parallel 3-phase exclusive scan ----
__global__ __launch_bounds__(256) void scan1_kernel(const int* __restrict__ deg,
                                                    int* __restrict__ local,
                                                    int* __restrict__ bsum, int n) {
  int t = threadIdx.x, i = blockIdx.x * 256 + t;
  int lane = t & 63, wid = t >> 6;
  __shared__ int ws[4];
  int v = (i < n) ? deg[i] : 0;
  int sc = v;
#pragma unroll
  for (int off = 1; off < 64; off <<= 1) {
    int u = __shfl_up(sc, off, 64);
    if (lane >= off) sc += u;
  }
  if (lane == 63) ws[wid] = sc;
  __syncthreads();
  int add = 0;
#pragma unroll
  for (int w = 0; w < 4; ++w) add += (w < wid) ? ws[w] : 0;
  if (i < n) local[i] = add + sc - v;
  if (t == 0) bsum[blockIdx.x] = ws[0] + ws[1] + ws[2] + ws[3];
}

__global__ __launch_bounds__(256) void scan2_kernel(int* __restrict__ bsum, int nb) {
  int t = threadIdx.x;
  int lane = t & 63, wid = t >> 6;
  __shared__ int ws[4];
  int v = (t < nb) ? bsum[t] : 0;
  int sc = v;
#pragma unroll
  for (int off = 1; off < 64; off <<= 1) {
    int u = __shfl_up(sc, off, 64);
    if (lane >= off) sc += u;
  }
  if (lane == 63) ws[wid] = sc;
  __syncthreads();
  int add = 0;
#pragma unroll
  for (int w = 0; w < 4; ++w) add += (w < wid) ? ws[w] : 0;
  if (t < nb) bsum[t] = add + sc - v;
}

__global__ __launch_bounds__(256) void scan3_kernel(const int* __restrict__ deg,
                                                    const int* __restrict__ local,
                                                    const int* __restrict__ bsum,
                                                    int* __restrict__ row_start,
                                                    int* __restrict__ cursor,
                                                    float* __restrict__ inv_deg, int n, int E) {
  int i = blockIdx.x * 256 + threadIdx.x;
  if (i < n) {
    int rs = local[i] + bsum[blockIdx.x];
    row_start[i] = rs;
    cursor[i] = rs;
    inv_deg[i] = 1.0f / fmaxf((float)deg[i], 1.0f);
  }
  if (i == 0) row_start[n] = E;
}

// ------------------------------------------------------- XCD-binned CSR fill
// u16 col (N < 65536) + non-temporal edge-stream loads so the streamed edges
// don't evict partially-filled col lines from the XCD's L2.
#define FILL_CH 4096
__global__ __launch_bounds__(256) void fill_binned_kernel(const int* __restrict__ src,
                                                          const int* __restrict__ dst,
                                                          int* cursor,
                                                          unsigned short* __restrict__ col,
                                                          int E) {
  int xcd = blockIdx.x & 7;
  int base = (blockIdx.x >> 3) * FILL_CH + threadIdx.x;
#pragma unroll
  for (int it = 0; it < FILL_CH / 256; ++it) {
    int e = base + it * 256;
    if (e < E) {
      int d = __builtin_nontemporal_load(dst + e);
      if (((d >> 5) & 7) == xcd) {
        int s = __builtin_nontemporal_load(src + e);
        int p = atomicAdd(&cursor[d], 1);
        col[p] = (unsigned short)s;
      }
    }
  }
}

// ------------------------------------------------ fp32 -> fp16 row convert (x)
__global__ __launch_bounds__(256) void to_f16_kernel(const float* __restrict__ in, int ld,
                                                     unsigned short* __restrict__ out, int ldo,
                                                     int nrows) {
  int idx = blockIdx.x * 256 + threadIdx.x;
  int r = idx >> 4, cc = (idx & 15) * 8;
  if (r >= nrows) return;
  const float* p = in + (size_t)r * ld + cc;
  float4 a = *reinterpret_cast<const float4*>(p);
  float4 b = *reinterpret_cast<const float4*>(p + 4);
  __half2 h0 = __floats2half2_rn(a.x, a.y);
  __half2 h1 = __floats2half2_rn(a.z, a.w);
  __half2 h2 = __floats2half2_rn(b.x, b.y);
  __half2 h3 = __floats2half2_rn(b.z, b.w);
  uint4 o;
  o.x = *reinterpret_cast<unsigned*>(&h0);
  o.y = *reinterpret_cast<unsigned*>(&h1);
  o.z = *reinterpret_cast<unsigned*>(&h2);
  o.w = *reinterpret_cast<unsigned*>(&h3);
  *reinterpret_cast<uint4*>(out + (size_t)r * ldo + cc) = o;
}

// -------------------------------------------------- weight prep (bf16 split)
__global__ __launch_bounds__(256) void prep_layer_w(const float* __restrict__ Wl,
                                                    const float* __restrict__ Wr,
                                                    bf16x8* __restrict__ f) {
  int idx = blockIdx.x * 256 + threadIdx.x;  // [0, 12288)
  int lane = idx & 63;
  int ksnt = (idx >> 6) & 31;
  int mat = (idx >> 11) & 1;
  int layer = idx >> 12;
  int ks = ksnt >> 3, nt = ksnt & 7;
  int nn = nt * 16 + (lane & 15);
  int k0 = ks * 32 + (lane >> 4) * 8;
  const float* W = (mat ? Wr : Wl) + (size_t)layer * DD * DD;
  float v[8];
#pragma unroll
  for (int j = 0; j < 8; ++j) v[j] = W[(size_t)(k0 + j) * DD + nn];
  bf16x8 hi, lo;
  split8(v, hi, lo);
  size_t base = (size_t)((layer * 2 + mat) * 2) * 2048 + (size_t)ksnt * 64 + lane;
  f[base] = hi;
  f[base + 2048] = lo;
}

__global__ __launch_bounds__(256) void prep_cls_w(const float* __restrict__ Wc1,
                                                  bf16x8* __restrict__ f) {
  int idx = blockIdx.x * 256 + threadIdx.x;  // [0, 3072)
  if (idx >= 3072) return;
  int lane = idx & 63;
  int ksnt = idx >> 6;
  int ks = ksnt >> 2, nt = ksnt & 3;
  int nn = nt * 16 + (lane & 15);
  int k0 = ks * 32 + (lane >> 4) * 8;
  float v[8];
#pragma unroll
  for (int j = 0; j < 8; ++j) v[j] = Wc1[(size_t)(k0 + j) * 64 + nn];
  bf16x8 hi, lo;
  split8(v, hi, lo);
  f[idx] = hi;
  f[idx + 3072] = lo;
}

// ------------------------------------------------------------- aggregation
// fp16 gather with pitch (x16: 128, jk16 slice: 384). Output agg16 fp16.
__global__ __launch_bounds__(256) void agg16_kernel(const unsigned short* __restrict__ h16,
                                                    int ldh,
                                                    const int* __restrict__ row_start,
                                                    const unsigned short* __restrict__ col,
                                                    const float* __restrict__ inv_deg,
                                                    unsigned short* __restrict__ agg16, int n) {
  int wib = threadIdx.x >> 6;
  int lane = threadIdx.x & 63;
  int node = blockIdx.x * 4 + wib;
  if (node >= n) return;
  int beg = row_start[node];
  int end = row_start[node + 1];
  int q = lane >> 4, l15 = lane & 15;
  float acc[8];
#pragma unroll
  for (int k = 0; k < 8; ++k) acc[k] = 0.f;

  for (int j0 = beg; j0 < end; j0 += 64) {
    int cnt = min(64, end - j0);
    int cidx = (int)col[j0 + min(lane, cnt - 1)];
    for (int j = 0; j < cnt; j += 4) {
      int e = j + q;
      int s = __shfl(cidx, e < cnt ? e : 0);
      if (e < cnt) {
        uint4 raw = *reinterpret_cast<const uint4*>(h16 + (size_t)s * ldh + l15 * 8);
        float f8[8];
        h8_to_f8(raw, f8);
#pragma unroll
        for (int k = 0; k < 8; ++k) acc[k] += f8[k];
      }
    }
  }
#pragma unroll
  for (int m = 16; m <= 32; m <<= 1) {
#pragma unroll
    for (int k = 0; k < 8; ++k) acc[k] += __shfl_xor(acc[k], m);
  }
  if (lane < 16) {
    float w = inv_deg[node];
    __half2 h0 = __floats2half2_rn(acc[0] * w, acc[1] * w);
    __half2 h1 = __floats2half2_rn(acc[2] * w, acc[3] * w);
    __half2 h2 = __floats2half2_rn(acc[4] * w, acc[5] * w);
    __half2 h3 = __floats2half2_rn(acc[6] * w, acc[7] * w);
    uint4 o;
    o.x = *reinterpret_cast<unsigned*>(&h0);
    o.y = *reinterpret_cast<unsigned*>(&h1);
    o.z = *reinterpret_cast<unsigned*>(&h2);
    o.w = *reinterpret_cast<unsigned*>(&h3);
    *reinterpret_cast<uint4*>(agg16 + (size_t)node * DD + l15 * 8) = o;
  }
}

// ---------------------------------------- MFMA layer GEMM + BN + ReLU (no LDS)
// A = agg16 (fp16). H = x (fp32, layer 0) or jk16 prev slice (fp16).
// Output: fp16 into jk16 slice only.
__global__ __launch_bounds__(256) void layer_gemm_mfma(
    const float* __restrict__ hin32, const unsigned short* __restrict__ hin16, int ldh,
    const unsigned short* __restrict__ agg16,
    const bf16x8* __restrict__ Blh_g, const bf16x8* __restrict__ Bll_g,
    const bf16x8* __restrict__ Brh_g, const bf16x8* __restrict__ Brl_g,
    const float* __restrict__ bl, const float* __restrict__ gamma,
    const float* __restrict__ beta, const float* __restrict__ rmean,
    const float* __restrict__ rvar, unsigned short* __restrict__ out16, int n) {
  int t = threadIdx.x;
  int w = t >> 6, lane = t & 63;
  int lane16 = lane & 15, quad = lane >> 4;
  int row0 = blockIdx.x * 64;
  int m = row0 + w * 16 + lane16;
  bool valid = m < n;
  size_t mrow = (size_t)(valid ? m : 0);
  const unsigned short* ap = agg16 + mrow * DD + quad * 8;

  bf16x8 Ah[4], Al[4], Hh[4], Hl[4];
#pragma unroll
  for (int ks = 0; ks < 4; ++ks) {
    float a8[8], h8[8];
    if (valid) {
      uint4 raw = *reinterpret_cast<const uint4*>(ap + ks * 32);
      h8_to_f8(raw, a8);
      if (hin16) {
        uint4 rh = *reinterpret_cast<const uint4*>(hin16 + mrow * (size_t)ldh + quad * 8 + ks * 32);
        h8_to_f8(rh, h8);
      } else {
        const float* hp = hin32 + mrow * (size_t)ldh + quad * 8 + ks * 32;
        *reinterpret_cast<float4*>(h8) = *reinterpret_cast<const float4*>(hp);
        *reinterpret_cast<float4*>(h8 + 4) = *reinterpret_cast<const float4*>(hp + 4);
      }
    } else {
#pragma unroll
      for (int j = 0; j < 8; ++j) { a8[j] = 0.f; h8[j] = 0.f; }
    }
    split8(a8, Ah[ks], Al[ks]);
    split8(h8, Hh[ks], Hl[ks]);
  }

  f32x4 acc[8];
#pragma unroll
  for (int nt = 0; nt < 8; ++nt) acc[nt] = (f32x4){0.f, 0.f, 0.f, 0.f};

#pragma unroll
  for (int ks = 0; ks < 4; ++ks) {
    int fb = ks * 8 * 64 + lane;
    bf16x8 B0[8], B1[8];
#pragma unroll
    for (int nt = 0; nt < 8; ++nt) B0[nt] = Blh_g[fb + nt * 64];
#pragma unroll
    for (int nt = 0; nt < 8; ++nt) acc[nt] = MFMA(Ah[ks], B0[nt], acc[nt]);
#pragma unroll
    for (int nt = 0; nt < 8; ++nt) B1[nt] = Bll_g[fb + nt * 64];
#pragma unroll
    for (int nt = 0; nt < 8; ++nt) acc[nt] = MFMA(Al[ks], B0[nt], acc[nt]);
#pragma unroll
    for (int nt = 0; nt < 8; ++nt) acc[nt] = MFMA(Ah[ks], B1[nt], acc[nt]);
#pragma unroll
    for (int nt = 0; nt < 8; ++nt) B0[nt] = Brh_g[fb + nt * 64];
#pragma unroll
    for (int nt = 0; nt < 8; ++nt) acc[nt] = MFMA(Hh[ks], B0[nt], acc[nt]);
#pragma unroll
    for (int nt = 0; nt < 8; ++nt) B1[nt] = Brl_g[fb + nt * 64];
#pragma unroll
    for (int nt = 0; nt < 8; ++nt) acc[nt] = MFMA(Hl[ks], B0[nt], acc[nt]);
#pragma unroll
    for (int nt = 0; nt < 8; ++nt) acc[nt] = MFMA(Hh[ks], B1[nt], acc[nt]);
  }

#pragma unroll
  for (int nt = 0; nt < 8; ++nt) {
    int c = nt * 16 + lane16;
    float sc = gamma[c] * rsqrtf(rvar[c] + EPSV);
    float sh = (bl[c] - rmean[c]) * sc + beta[c];
#pragma unroll
    for (int r = 0; r < 4; ++r) {
      int orow = row0 + w * 16 + quad * 4 + r;
      if (orow < n) {
        float v = fmaxf(fmaf(acc[nt][r], sc, sh), 0.f);
        __half hv = __float2half_rn(v);
        out16[(size_t)orow * JKD + c] = *reinterpret_cast<unsigned short*>(&hv);
      }
    }
  }
}

// ------------------------------------------------------ MFMA classifier
__global__ __launch_bounds__(256) void classifier_mfma(
    const unsigned short* __restrict__ jk16, const bf16x8* __restrict__ Bh_g,
    const bf16x8* __restrict__ Bl_g, const float* __restrict__ bc1,
    const float* __restrict__ Wc2, const float* __restrict__ bc2,
    float* __restrict__ out, int n) {
  __shared__ float sZ[64][65];
  int t = threadIdx.x;
  int w = t >> 6, lane = t & 63;
  int lane16 = lane & 15, quad = lane >> 4;
  int row0 = blockIdx.x * 64;
  int m = row0 + w * 16 + lane16;
  bool valid = m < n;
  const unsigned short* jp = jk16 + (size_t)(valid ? m : 0) * JKD + quad * 8;

  f32x4 acc[4];
#pragma unroll
  for (int nt = 0; nt < 4; ++nt) acc[nt] = (f32x4){0.f, 0.f, 0.f, 0.f};

#pragma unroll
  for (int ks = 0; ks < 12; ++ks) {
    float a8[8];
    if (valid) {
      uint4 raw = *reinterpret_cast<const uint4*>(jp + ks * 32);
      h8_to_f8(raw, a8);
    } else {
#pragma unroll
      for (int j = 0; j < 8; ++j) a8[j] = 0.f;
    }
    bf16x8 Jh, Jl;
    split8(a8, Jh, Jl);
    int fb = ks * 4 * 64 + lane;
    bf16x8 B0[4], B1[4];
#pragma unroll
    for (int nt = 0; nt < 4; ++nt) B0[nt] = Bh_g[fb + nt * 64];
#pragma unroll
    for (int nt = 0; nt < 4; ++nt) acc[nt] = MFMA(Jh, B0[nt], acc[nt]);
#pragma unroll
    for (int nt = 0; nt < 4; ++nt) B1[nt] = Bl_g[fb + nt * 64];
#pragma unroll
    for (int nt = 0; nt < 4; ++nt) acc[nt] = MFMA(Jl, B0[nt], acc[nt]);
#pragma unroll
    for (int nt = 0; nt < 4; ++nt) acc[nt] = MFMA(Jh, B1[nt], acc[nt]);
  }

#pragma unroll
  for (int nt = 0; nt < 4; ++nt) {
    int c = nt * 16 + lane16;
    float b1 = bc1[c];
#pragma unroll
    for (int r = 0; r < 4; ++r)
      sZ[w * 16 + quad * 4 + r][c] = fmaxf(acc[nt][r] + b1, 0.f);
  }
  __syncthreads();

  if (t < 128) {
    int r = t >> 1, j = t & 1;
    int gr = row0 + r;
    if (gr < n) {
      float s = bc2[j];
#pragma unroll
      for (int c = 0; c < 64; ++c) s = fmaf(sZ[r][c], Wc2[c * 2 + j], s);
      out[(size_t)gr * 2 + j] = s;
    }
  }
}

// ----------------------------------------------------------------- launch

extern "C" void kernel_launch(void* const* d_in, const int* in_sizes, int n_in,
                              void* d_out, int out_size, void* d_ws, size_t ws_size,
                              hipStream_t stream) {
  const float* x = (const float*)d_in[0];
  const int* ei = (const int*)d_in[1];
  const float* Wl = (const float*)d_in[2];
  const float* bl = (const float*)d_in[3];
  const float* Wr = (const float*)d_in[4];
  const float* gamma = (const float*)d_in[5];
  const float* beta = (const float*)d_in[6];
  const float* rmean = (const float*)d_in[7];
  const float* rvar = (const float*)d_in[8];
  const float* Wc1 = (const float*)d_in[9];
  const float* bc1 = (const float*)d_in[10];
  const float* Wc2 = (const float*)d_in[11];
  const float* bc2 = (const float*)d_in[12];
  float* out = (float*)d_out;

  const int N = in_sizes[0] / DD;
  const int E = in_sizes[1] / 2;
  const int* src = ei;
  const int* dst = ei + E;

  auto align = [](size_t v) { return (v + 255) & ~(size_t)255; };
  char* ws = (char*)d_ws;
  size_t off = 0;
  int* deg = (int*)(ws + off);       off = align(off + sizeof(int) * (size_t)N);
  int* row_start = (int*)(ws + off); off = align(off + sizeof(int) * (size_t)(N + 1));
  int* cursor = (int*)(ws + off);    off = align(off + sizeof(int) * (size_t)N);
  unsigned short* col = (unsigned short*)(ws + off); off = align(off + sizeof(short) * (size_t)E);
  float* inv_deg = (float*)(ws + off); off = align(off + sizeof(float) * (size_t)N);
  int* slocal = (int*)(ws + off);    off = align(off + sizeof(int) * (size_t)N);
  int* bsum = (int*)(ws + off);      off = align(off + sizeof(int) * 256);
  unsigned short* x16 = (unsigned short*)(ws + off);  off = align(off + sizeof(short) * (size_t)N * DD);
  unsigned short* agg16 = (unsigned short*)(ws + off); off = align(off + sizeof(short) * (size_t)N * DD);
  unsigned short* jk16 = (unsigned short*)(ws + off); off = align(off + sizeof(short) * (size_t)N * JKD);
  bf16x8* wf = (bf16x8*)(ws + off);  off = align(off + (size_t)16 * 3 * 2 * 2 * 2048);
  bf16x8* wcf = (bf16x8*)(ws + off); off = align(off + (size_t)16 * 2 * 3072);

  const int nb = (N + 255) / 256;
  zero_int_kernel<<<(N + 255) / 256, 256, 0, stream>>>(deg, N);
  degree_kernel<<<(E + 255) / 256, 256, 0, stream>>>(dst, deg, E);
  scan1_kernel<<<nb, 256, 0, stream>>>(deg, slocal, bsum, N);
  scan2_kernel<<<1, 256, 0, stream>>>(bsum, nb);
  scan3_kernel<<<nb, 256, 0, stream>>>(deg, slocal, bsum, row_start, cursor, inv_deg, N, E);
  {
    int nChunks = (E + FILL_CH - 1) / FILL_CH;
    fill_binned_kernel<<<nChunks * 8, 256, 0, stream>>>(src, dst, cursor, col, E);
  }
  prep_layer_w<<<48, 256, 0, stream>>>(Wl, Wr, wf);
  prep_cls_w<<<12, 256, 0, stream>>>(Wc1, wcf);
  to_f16_kernel<<<(N * 16 + 255) / 256, 256, 0, stream>>>(x, DD, x16, DD, N);

  int nTiles = (N + 63) / 64;
  for (int i = 0; i < 3; ++i) {
    const unsigned short* gsrc = (i == 0) ? x16 : (jk16 + (size_t)(i - 1) * DD);
    int ldg = (i == 0) ? DD : JKD;
    agg16_kernel<<<(N + 3) / 4, 256, 0, stream>>>(gsrc, ldg, row_start, col, inv_deg, agg16, N);
    bf16x8* Wlf = wf + (size_t)(i * 2 + 0) * 2 * 2048;
    bf16x8* Wrf = wf + (size_t)(i * 2 + 1) * 2 * 2048;
    layer_gemm_mfma<<<nTiles, 256, 0, stream>>>(
        (i == 0) ? x : nullptr,
        (i == 0) ? (const unsigned short*)nullptr : (jk16 + (size_t)(i - 1) * DD),
        (i == 0) ? DD : JKD, agg16, Wlf, Wlf + 2048, Wrf, Wrf + 2048,
        bl + (size_t)i * DD, gamma + (size_t)i * DD, beta + (size_t)i * DD,
        rmean + (size_t)i * DD, rvar + (size_t)i * DD, jk16 + (size_t)i * DD, N);
  }
  classifier_mfma<<<nTiles, 256, 0, stream>>>(jk16, wcf, wcf + 3072, bc1, Wc2, bc2, out, N);
}

// Round 7
// 365.061 us; speedup vs baseline: 2.3142x; 1.0447x over previous
//
#include <hip/hip_runtime.h>
#include <hip/hip_fp16.h>
#include <cstdint>
#include <cstddef>

#define DD 128
#define JKD 384
#define EPSV 1e-5f
#define BSH 7          // bucket = dst >> 7 (128 nodes/bucket)
#define NBMAX 512      // N < 65536 (u16 col) -> <= 512 buckets
#define PCH 8192       // partition chunk (edges per block)
#define BCAP 8192      // per-bucket LDS staging capacity (pass C)

typedef __attribute__((ext_vector_type(8))) short bf16x8;
typedef __attribute__((ext_vector_type(4))) float f32x4;
#define MFMA(a, b, c) __builtin_amdgcn_mfma_f32_16x16x32_bf16(a, b, c, 0, 0, 0)

__device__ inline unsigned short f2bf_rne(float f) {
  unsigned u = __float_as_uint(f);
  unsigned r = u + 0x7fffu + ((u >> 16) & 1u);
  return (unsigned short)(r >> 16);
}

__device__ inline void split8(const float* s, bf16x8& hi, bf16x8& lo) {
#pragma unroll
  for (int j = 0; j < 8; ++j) {
    float f = s[j];
    unsigned short h = f2bf_rne(f);
    float fh = __uint_as_float((unsigned)h << 16);
    hi[j] = (short)h;
    lo[j] = (short)f2bf_rne(f - fh);
  }
}

__device__ inline void h8_to_f8(uint4 raw, float* out) {
  const __half2* hp = reinterpret_cast<const __half2*>(&raw);
#pragma unroll
  for (int j = 0; j < 4; ++j) {
    float2 f = __half22float2(hp[j]);
    out[2 * j] = f.x;
    out[2 * j + 1] = f.y;
  }
}

// ---------------------------------------------------------------- utilities

__global__ void zero_int_kernel(int* __restrict__ p, int n) {
  int i = blockIdx.x * blockDim.x + threadIdx.x;
  if (i < n) p[i] = 0;
}

// ----------------------------------------------- pass A: bucket histogram
__global__ __launch_bounds__(256) void bucket_hist(const int* __restrict__ dst,
                                                   int* __restrict__ bucket_cnt, int E) {
  __shared__ int h[NBMAX];
  int t = threadIdx.x;
  for (int i = t; i < NBMAX; i += 256) h[i] = 0;
  __syncthreads();
  int base = blockIdx.x * PCH;
#pragma unroll
  for (int it = 0; it < PCH / 256; ++it) {
    int e = base + it * 256 + t;
    if (e < E) {
      int d = __builtin_nontemporal_load(dst + e);
      atomicAdd(&h[d >> BSH], 1);
    }
  }
  __syncthreads();
  for (int i = t; i < NBMAX; i += 256)
    if (h[i]) atomicAdd(&bucket_cnt[i], h[i]);
}

// ----------------------------------------------- pass S: scan bucket counts
__global__ __launch_bounds__(512) void bucket_scan(const int* __restrict__ bucket_cnt,
                                                   int* __restrict__ bucket_start,
                                                   int* __restrict__ bucket_cursor,
                                                   int* __restrict__ row_start, int N, int E) {
  __shared__ int wsum[8];
  __shared__ int wpref[8];
  int t = threadIdx.x;
  int lane = t & 63, wid = t >> 6;
  int v = bucket_cnt[t];
  int sc = v;
#pragma unroll
  for (int off = 1; off < 64; off <<= 1) {
    int u = __shfl_up(sc, off, 64);
    if (lane >= off) sc += u;
  }
  if (lane == 63) wsum[wid] = sc;
  __syncthreads();
  if (t == 0) {
    int a = 0;
#pragma unroll
    for (int w = 0; w < 8; ++w) { wpref[w] = a; a += wsum[w]; }
  }
  __syncthreads();
  int excl = wpref[wid] + sc - v;
  bucket_start[t] = excl;
  bucket_cursor[t] = excl;
  if (t == 0) row_start[N] = E;
}

// ----------------------------------------------- pass B: coalesced partition
// Stage chunk's edges grouped by bucket in LDS, reserve one contiguous global
// run per (chunk,bucket), copy runs out wave-coalesced. packed = (d&127)<<16|src.
__global__ __launch_bounds__(256) void partition_kernel(const int* __restrict__ src,
                                                        const int* __restrict__ dst,
                                                        int* bucket_cursor,
                                                        unsigned* __restrict__ packed, int E) {
  __shared__ int h[NBMAX];
  __shared__ int lofs[NBMAX];
  __shared__ int res[NBMAX];
  __shared__ int lcur[NBMAX];
  __shared__ int wsum[4];
  __shared__ int wpref[4];
  __shared__ unsigned stage[PCH];
  int t = threadIdx.x;
  int lane = t & 63, wid = t >> 6;
  int base = blockIdx.x * PCH;
  int csz = min(PCH, E - base);

  for (int i = t; i < NBMAX; i += 256) h[i] = 0;
  __syncthreads();
#pragma unroll
  for (int it = 0; it < PCH / 256; ++it) {
    int e = base + it * 256 + t;
    if (e < E) {
      int d = __builtin_nontemporal_load(dst + e);
      atomicAdd(&h[d >> BSH], 1);
    }
  }
  __syncthreads();
  // scan 512 bins with 256 threads (thread t owns bins 2t, 2t+1)
  int c0 = h[2 * t], c1 = h[2 * t + 1];
  int s = c0 + c1;
  int sc = s;
#pragma unroll
  for (int off = 1; off < 64; off <<= 1) {
    int u = __shfl_up(sc, off, 64);
    if (lane >= off) sc += u;
  }
  if (lane == 63) wsum[wid] = sc;
  __syncthreads();
  if (t == 0) {
    int a = 0;
#pragma unroll
    for (int w = 0; w < 4; ++w) { wpref[w] = a; a += wsum[w]; }
  }
  __syncthreads();
  int excl = wpref[wid] + sc - s;
  lofs[2 * t] = excl;
  lofs[2 * t + 1] = excl + c0;
  lcur[2 * t] = excl;
  lcur[2 * t + 1] = excl + c0;
  if (c0 > 0) res[2 * t] = atomicAdd(&bucket_cursor[2 * t], c0);
  if (c1 > 0) res[2 * t + 1] = atomicAdd(&bucket_cursor[2 * t + 1], c1);
  __syncthreads();
#pragma unroll
  for (int it = 0; it < PCH / 256; ++it) {
    int e = base + it * 256 + t;
    if (e < E) {
      int d = __builtin_nontemporal_load(dst + e);
      int sv = __builtin_nontemporal_load(src + e);
      int pos = atomicAdd(&lcur[d >> BSH], 1);
      stage[pos] = ((unsigned)(d & ((1 << BSH) - 1)) << 16) | (unsigned)(sv & 0xffff);
    }
  }
  __syncthreads();
  // copy runs out: wave w handles buckets w, w+4, ...
  for (int b = wid; b < NBMAX; b += 4) {
    int run = h[b];
    if (run == 0) continue;
    int gbase = res[b], lbase = lofs[b];
    for (int j = lane; j < run; j += 64) packed[gbase + j] = stage[lbase + j];
  }
}

// ----------------------------------------------- pass C: per-bucket CSR build
__global__ __launch_bounds__(256) void csr_build(const unsigned* __restrict__ packed,
                                                 const int* __restrict__ bucket_start,
                                                 int* __restrict__ row_start,
                                                 float* __restrict__ inv_deg,
                                                 unsigned short* __restrict__ col, int N) {
  __shared__ int cntA[128];
  __shared__ int lcur[128];
  __shared__ int wsum2[2];
  __shared__ int wpref2[2];
  __shared__ unsigned short stage[BCAP];
  int t = threadIdx.x;
  int b = blockIdx.x;
  int s0 = bucket_start[b], s1 = bucket_start[b + 1];
  int cnt = s1 - s0;
  if (t < 128) cntA[t] = 0;
  __syncthreads();
  for (int i = t; i < cnt; i += 256) {
    unsigned p = packed[s0 + i];
    atomicAdd(&cntA[p >> 16], 1);
  }
  __syncthreads();
  if (t < 128) {
    int lane = t & 63, wid = t >> 6;
    int v = cntA[t];
    int sc = v;
#pragma unroll
    for (int off = 1; off < 64; off <<= 1) {
      int u = __shfl_up(sc, off, 64);
      if (lane >= off) sc += u;
    }
    if (lane == 63) wsum2[wid] = sc;
    // wave-level barrier is implicit within wave; need cross-wave:
    __syncthreads();
    if (t == 0) { wpref2[0] = 0; wpref2[1] = wsum2[0]; }
    __syncthreads();
    int excl = wpref2[wid] + sc - v;
    lcur[t] = excl;
    int node = b * 128 + t;
    if (node < N) {
      row_start[node] = s0 + excl;
      inv_deg[node] = 1.0f / fmaxf((float)v, 1.0f);
    }
  } else {
    __syncthreads();
    __syncthreads();
  }
  __syncthreads();
  for (int i = t; i < cnt; i += 256) {
    unsigned p = packed[s0 + i];
    int pos = atomicAdd(&lcur[p >> 16], 1);
    unsigned short us = (unsigned short)(p & 0xffff);
    if (pos < BCAP) stage[pos] = us;
    else col[s0 + pos] = us;
  }
  __syncthreads();
  int lim = min(cnt, BCAP);
  for (int i = t; i < lim; i += 256) col[s0 + i] = stage[i];
}

// ------------------------------------------------ fp32 -> fp16 row convert (x)
__global__ __launch_bounds__(256) void to_f16_kernel(const float* __restrict__ in, int ld,
                                                     unsigned short* __restrict__ out, int ldo,
                                                     int nrows) {
  int idx = blockIdx.x * 256 + threadIdx.x;
  int r = idx >> 4, cc = (idx & 15) * 8;
  if (r >= nrows) return;
  const float* p = in + (size_t)r * ld + cc;
  float4 a = *reinterpret_cast<const float4*>(p);
  float4 b = *reinterpret_cast<const float4*>(p + 4);
  __half2 h0 = __floats2half2_rn(a.x, a.y);
  __half2 h1 = __floats2half2_rn(a.z, a.w);
  __half2 h2 = __floats2half2_rn(b.x, b.y);
  __half2 h3 = __floats2half2_rn(b.z, b.w);
  uint4 o;
  o.x = *reinterpret_cast<unsigned*>(&h0);
  o.y = *reinterpret_cast<unsigned*>(&h1);
  o.z = *reinterpret_cast<unsigned*>(&h2);
  o.w = *reinterpret_cast<unsigned*>(&h3);
  *reinterpret_cast<uint4*>(out + (size_t)r * ldo + cc) = o;
}

// -------------------------------------------------- weight prep (bf16 split)
__global__ __launch_bounds__(256) void prep_layer_w(const float* __restrict__ Wl,
                                                    const float* __restrict__ Wr,
                                                    bf16x8* __restrict__ f) {
  int idx = blockIdx.x * 256 + threadIdx.x;  // [0, 12288)
  int lane = idx & 63;
  int ksnt = (idx >> 6) & 31;
  int mat = (idx >> 11) & 1;
  int layer = idx >> 12;
  int ks = ksnt >> 3, nt = ksnt & 7;
  int nn = nt * 16 + (lane & 15);
  int k0 = ks * 32 + (lane >> 4) * 8;
  const float* W = (mat ? Wr : Wl) + (size_t)layer * DD * DD;
  float v[8];
#pragma unroll
  for (int j = 0; j < 8; ++j) v[j] = W[(size_t)(k0 + j) * DD + nn];
  bf16x8 hi, lo;
  split8(v, hi, lo);
  size_t base = (size_t)((layer * 2 + mat) * 2) * 2048 + (size_t)ksnt * 64 + lane;
  f[base] = hi;
  f[base + 2048] = lo;
}

__global__ __launch_bounds__(256) void prep_cls_w(const float* __restrict__ Wc1,
                                                  bf16x8* __restrict__ f) {
  int idx = blockIdx.x * 256 + threadIdx.x;  // [0, 3072)
  if (idx >= 3072) return;
  int lane = idx & 63;
  int ksnt = idx >> 6;
  int ks = ksnt >> 2, nt = ksnt & 3;
  int nn = nt * 16 + (lane & 15);
  int k0 = ks * 32 + (lane >> 4) * 8;
  float v[8];
#pragma unroll
  for (int j = 0; j < 8; ++j) v[j] = Wc1[(size_t)(k0 + j) * 64 + nn];
  bf16x8 hi, lo;
  split8(v, hi, lo);
  f[idx] = hi;
  f[idx + 3072] = lo;
}

// ------------------------------------------------------------- aggregation
__global__ __launch_bounds__(256) void agg16_kernel(const unsigned short* __restrict__ h16,
                                                    int ldh,
                                                    const int* __restrict__ row_start,
                                                    const unsigned short* __restrict__ col,
                                                    const float* __restrict__ inv_deg,
                                                    unsigned short* __restrict__ agg16, int n) {
  int wib = threadIdx.x >> 6;
  int lane = threadIdx.x & 63;
  int node = blockIdx.x * 4 + wib;
  if (node >= n) return;
  int beg = row_start[node];
  int end = row_start[node + 1];
  int q = lane >> 4, l15 = lane & 15;
  float acc[8];
#pragma unroll
  for (int k = 0; k < 8; ++k) acc[k] = 0.f;

  for (int j0 = beg; j0 < end; j0 += 64) {
    int cnt = min(64, end - j0);
    int cidx = (int)col[j0 + min(lane, cnt - 1)];
    for (int j = 0; j < cnt; j += 4) {
      int e = j + q;
      int s = __shfl(cidx, e < cnt ? e : 0);
      if (e < cnt) {
        uint4 raw = *reinterpret_cast<const uint4*>(h16 + (size_t)s * ldh + l15 * 8);
        float f8[8];
        h8_to_f8(raw, f8);
#pragma unroll
        for (int k = 0; k < 8; ++k) acc[k] += f8[k];
      }
    }
  }
#pragma unroll
  for (int m = 16; m <= 32; m <<= 1) {
#pragma unroll
    for (int k = 0; k < 8; ++k) acc[k] += __shfl_xor(acc[k], m);
  }
  if (lane < 16) {
    float w = inv_deg[node];
    __half2 h0 = __floats2half2_rn(acc[0] * w, acc[1] * w);
    __half2 h1 = __floats2half2_rn(acc[2] * w, acc[3] * w);
    __half2 h2 = __floats2half2_rn(acc[4] * w, acc[5] * w);
    __half2 h3 = __floats2half2_rn(acc[6] * w, acc[7] * w);
    uint4 o;
    o.x = *reinterpret_cast<unsigned*>(&h0);
    o.y = *reinterpret_cast<unsigned*>(&h1);
    o.z = *reinterpret_cast<unsigned*>(&h2);
    o.w = *reinterpret_cast<unsigned*>(&h3);
    *reinterpret_cast<uint4*>(agg16 + (size_t)node * DD + l15 * 8) = o;
  }
}

// ---------------------------------------- MFMA layer GEMM + BN + ReLU (no LDS)
__global__ __launch_bounds__(256) void layer_gemm_mfma(
    const float* __restrict__ hin32, const unsigned short* __restrict__ hin16, int ldh,
    const unsigned short* __restrict__ agg16,
    const bf16x8* __restrict__ Blh_g, const bf16x8* __restrict__ Bll_g,
    const bf16x8* __restrict__ Brh_g, const bf16x8* __restrict__ Brl_g,
    const float* __restrict__ bl, const float* __restrict__ gamma,
    const float* __restrict__ beta, const float* __restrict__ rmean,
    const float* __restrict__ rvar, unsigned short* __restrict__ out16, int n) {
  int t = threadIdx.x;
  int w = t >> 6, lane = t & 63;
  int lane16 = lane & 15, quad = lane >> 4;
  int row0 = blockIdx.x * 64;
  int m = row0 + w * 16 + lane16;
  bool valid = m < n;
  size_t mrow = (size_t)(valid ? m : 0);
  const unsigned short* ap = agg16 + mrow * DD + quad * 8;

  bf16x8 Ah[4], Al[4], Hh[4], Hl[4];
#pragma unroll
  for (int ks = 0; ks < 4; ++ks) {
    float a8[8], h8[8];
    if (valid) {
      uint4 raw = *reinterpret_cast<const uint4*>(ap + ks * 32);
      h8_to_f8(raw, a8);
      if (hin16) {
        uint4 rh = *reinterpret_cast<const uint4*>(hin16 + mrow * (size_t)ldh + quad * 8 + ks * 32);
        h8_to_f8(rh, h8);
      } else {
        const float* hp = hin32 + mrow * (size_t)ldh + quad * 8 + ks * 32;
        *reinterpret_cast<float4*>(h8) = *reinterpret_cast<const float4*>(hp);
        *reinterpret_cast<float4*>(h8 + 4) = *reinterpret_cast<const float4*>(hp + 4);
      }
    } else {
#pragma unroll
      for (int j = 0; j < 8; ++j) { a8[j] = 0.f; h8[j] = 0.f; }
    }
    split8(a8, Ah[ks], Al[ks]);
    split8(h8, Hh[ks], Hl[ks]);
  }

  f32x4 acc[8];
#pragma unroll
  for (int nt = 0; nt < 8; ++nt) acc[nt] = (f32x4){0.f, 0.f, 0.f, 0.f};

#pragma unroll
  for (int ks = 0; ks < 4; ++ks) {
    int fb = ks * 8 * 64 + lane;
    bf16x8 B0[8], B1[8];
#pragma unroll
    for (int nt = 0; nt < 8; ++nt) B0[nt] = Blh_g[fb + nt * 64];
#pragma unroll
    for (int nt = 0; nt < 8; ++nt) acc[nt] = MFMA(Ah[ks], B0[nt], acc[nt]);
#pragma unroll
    for (int nt = 0; nt < 8; ++nt) B1[nt] = Bll_g[fb + nt * 64];
#pragma unroll
    for (int nt = 0; nt < 8; ++nt) acc[nt] = MFMA(Al[ks], B0[nt], acc[nt]);
#pragma unroll
    for (int nt = 0; nt < 8; ++nt) acc[nt] = MFMA(Ah[ks], B1[nt], acc[nt]);
#pragma unroll
    for (int nt = 0; nt < 8; ++nt) B0[nt] = Brh_g[fb + nt * 64];
#pragma unroll
    for (int nt = 0; nt < 8; ++nt) acc[nt] = MFMA(Hh[ks], B0[nt], acc[nt]);
#pragma unroll
    for (int nt = 0; nt < 8; ++nt) B1[nt] = Brl_g[fb + nt * 64];
#pragma unroll
    for (int nt = 0; nt < 8; ++nt) acc[nt] = MFMA(Hl[ks], B0[nt], acc[nt]);
#pragma unroll
    for (int nt = 0; nt < 8; ++nt) acc[nt] = MFMA(Hh[ks], B1[nt], acc[nt]);
  }

#pragma unroll
  for (int nt = 0; nt < 8; ++nt) {
    int c = nt * 16 + lane16;
    float sc = gamma[c] * rsqrtf(rvar[c] + EPSV);
    float sh = (bl[c] - rmean[c]) * sc + beta[c];
#pragma unroll
    for (int r = 0; r < 4; ++r) {
      int orow = row0 + w * 16 + quad * 4 + r;
      if (orow < n) {
        float v = fmaxf(fmaf(acc[nt][r], sc, sh), 0.f);
        __half hv = __float2half_rn(v);
        out16[(size_t)orow * JKD + c] = *reinterpret_cast<unsigned short*>(&hv);
      }
    }
  }
}

// ------------------------------------------------------ MFMA classifier
__global__ __launch_bounds__(256) void classifier_mfma(
    const unsigned short* __restrict__ jk16, const bf16x8* __restrict__ Bh_g,
    const bf16x8* __restrict__ Bl_g, const float* __restrict__ bc1,
    const float* __restrict__ Wc2, const float* __restrict__ bc2,
    float* __restrict__ out, int n) {
  __shared__ float sZ[64][65];
  int t = threadIdx.x;
  int w = t >> 6, lane = t & 63;
  int lane16 = lane & 15, quad = lane >> 4;
  int row0 = blockIdx.x * 64;
  int m = row0 + w * 16 + lane16;
  bool valid = m < n;
  const unsigned short* jp = jk16 + (size_t)(valid ? m : 0) * JKD + quad * 8;

  f32x4 acc[4];
#pragma unroll
  for (int nt = 0; nt < 4; ++nt) acc[nt] = (f32x4){0.f, 0.f, 0.f, 0.f};

#pragma unroll
  for (int ks = 0; ks < 12; ++ks) {
    float a8[8];
    if (valid) {
      uint4 raw = *reinterpret_cast<const uint4*>(jp + ks * 32);
      h8_to_f8(raw, a8);
    } else {
#pragma unroll
      for (int j = 0; j < 8; ++j) a8[j] = 0.f;
    }
    bf16x8 Jh, Jl;
    split8(a8, Jh, Jl);
    int fb = ks * 4 * 64 + lane;
    bf16x8 B0[4], B1[4];
#pragma unroll
    for (int nt = 0; nt < 4; ++nt) B0[nt] = Bh_g[fb + nt * 64];
#pragma unroll
    for (int nt = 0; nt < 4; ++nt) acc[nt] = MFMA(Jh, B0[nt], acc[nt]);
#pragma unroll
    for (int nt = 0; nt < 4; ++nt) B1[nt] = Bl_g[fb + nt * 64];
#pragma unroll
    for (int nt = 0; nt < 4; ++nt) acc[nt] = MFMA(Jl, B0[nt], acc[nt]);
#pragma unroll
    for (int nt = 0; nt < 4; ++nt) acc[nt] = MFMA(Jh, B1[nt], acc[nt]);
  }

#pragma unroll
  for (int nt = 0; nt < 4; ++nt) {
    int c = nt * 16 + lane16;
    float b1 = bc1[c];
#pragma unroll
    for (int r = 0; r < 4; ++r)
      sZ[w * 16 + quad * 4 + r][c] = fmaxf(acc[nt][r] + b1, 0.f);
  }
  __syncthreads();

  if (t < 128) {
    int r = t >> 1, j = t & 1;
    int gr = row0 + r;
    if (gr < n) {
      float s = bc2[j];
#pragma unroll
      for (int c = 0; c < 64; ++c) s = fmaf(sZ[r][c], Wc2[c * 2 + j], s);
      out[(size_t)gr * 2 + j] = s;
    }
  }
}

// ----------------------------------------------------------------- launch

extern "C" void kernel_launch(void* const* d_in, const int* in_sizes, int n_in,
                              void* d_out, int out_size, void* d_ws, size_t ws_size,
                              hipStream_t stream) {
  const float* x = (const float*)d_in[0];
  const int* ei = (const int*)d_in[1];
  const float* Wl = (const float*)d_in[2];
  const float* bl = (const float*)d_in[3];
  const float* Wr = (const float*)d_in[4];
  const float* gamma = (const float*)d_in[5];
  const float* beta = (const float*)d_in[6];
  const float* rmean = (const float*)d_in[7];
  const float* rvar = (const float*)d_in[8];
  const float* Wc1 = (const float*)d_in[9];
  const float* bc1 = (const float*)d_in[10];
  const float* Wc2 = (const float*)d_in[11];
  const float* bc2 = (const float*)d_in[12];
  float* out = (float*)d_out;

  const int N = in_sizes[0] / DD;
  const int E = in_sizes[1] / 2;
  const int* src = ei;
  const int* dst = ei + E;

  auto align = [](size_t v) { return (v + 255) & ~(size_t)255; };
  char* ws = (char*)d_ws;
  size_t off = 0;
  int* row_start = (int*)(ws + off);  off = align(off + sizeof(int) * (size_t)(N + 1));
  unsigned short* col = (unsigned short*)(ws + off); off = align(off + sizeof(short) * (size_t)E);
  float* inv_deg = (float*)(ws + off); off = align(off + sizeof(float) * (size_t)N);
  unsigned* packed = (unsigned*)(ws + off); off = align(off + sizeof(unsigned) * (size_t)E);
  int* bucket_cnt = (int*)(ws + off);    off = align(off + sizeof(int) * NBMAX);
  int* bucket_start = (int*)(ws + off);  off = align(off + sizeof(int) * (NBMAX + 1));
  int* bucket_cursor = (int*)(ws + off); off = align(off + sizeof(int) * NBMAX);
  unsigned short* x16 = (unsigned short*)(ws + off);   off = align(off + sizeof(short) * (size_t)N * DD);
  unsigned short* agg16 = (unsigned short*)(ws + off); off = align(off + sizeof(short) * (size_t)N * DD);
  unsigned short* jk16 = (unsigned short*)(ws + off);  off = align(off + sizeof(short) * (size_t)N * JKD);
  bf16x8* wf = (bf16x8*)(ws + off);  off = align(off + (size_t)16 * 3 * 2 * 2 * 2048);
  bf16x8* wcf = (bf16x8*)(ws + off); off = align(off + (size_t)16 * 2 * 3072);

  const int nbuck = (N + 127) >> BSH;
  const int nChunks = (E + PCH - 1) / PCH;

  zero_int_kernel<<<(NBMAX + 255) / 256, 256, 0, stream>>>(bucket_cnt, NBMAX);
  bucket_hist<<<nChunks, 256, 0, stream>>>(dst, bucket_cnt, E);
  bucket_scan<<<1, 512, 0, stream>>>(bucket_cnt, bucket_start, bucket_cursor, row_start, N, E);
  partition_kernel<<<nChunks, 256, 0, stream>>>(src, dst, bucket_cursor, packed, E);
  csr_build<<<nbuck, 256, 0, stream>>>(packed, bucket_start, row_start, inv_deg, col, N);

  prep_layer_w<<<48, 256, 0, stream>>>(Wl, Wr, wf);
  prep_cls_w<<<12, 256, 0, stream>>>(Wc1, wcf);
  to_f16_kernel<<<(N * 16 + 255) / 256, 256, 0, stream>>>(x, DD, x16, DD, N);

  int nTiles = (N + 63) / 64;
  for (int i = 0; i < 3; ++i) {
    const unsigned short* gsrc = (i == 0) ? x16 : (jk16 + (size_t)(i - 1) * DD);
    int ldg = (i == 0) ? DD : JKD;
    agg16_kernel<<<(N + 3) / 4, 256, 0, stream>>>(gsrc, ldg, row_start, col, inv_deg, agg16, N);
    bf16x8* Wlf = wf + (size_t)(i * 2 + 0) * 2 * 2048;
    bf16x8* Wrf = wf + (size_t)(i * 2 + 1) * 2 * 2048;
    layer_gemm_mfma<<<nTiles, 256, 0, stream>>>(
        (i == 0) ? x : nullptr,
        (i == 0) ? (const unsigned short*)nullptr : (jk16 + (size_t)(i - 1) * DD),
        (i == 0) ? DD : JKD, agg16, Wlf, Wlf + 2048, Wrf, Wrf + 2048,
        bl + (size_t)i * DD, gamma + (size_t)i * DD, beta + (size_t)i * DD,
        rmean + (size_t)i * DD, rvar + (size_t)i * DD, jk16 + (size_t)i * DD, N);
  }
  classifier_mfma<<<nTiles, 256, 0, stream>>>(jk16, wcf, wcf + 3072, bc1, Wc2, bc2, out, N);
}

// Round 8
// 332.799 us; speedup vs baseline: 2.5385x; 1.0969x over previous
//
#include <hip/hip_runtime.h>
#include <hip/hip_fp16.h>
#include <cstdint>
#include <cstddef>

#define DD 128
#define JKD 384
#define EPSV 1e-5f
#define BSH 7          // bucket = dst >> 7 (128 nodes/bucket)
#define NBMAX 512      // N < 65536 (u16 col) -> <= 512 buckets
#define PCH 8192       // partition chunk (edges per block)
#define PTH 1024       // partition/hist block threads (16 waves -> latency hiding)
#define BCAP 8192      // per-bucket LDS staging capacity (pass C)

typedef __attribute__((ext_vector_type(8))) short bf16x8;
typedef __attribute__((ext_vector_type(4))) float f32x4;
#define MFMA(a, b, c) __builtin_amdgcn_mfma_f32_16x16x32_bf16(a, b, c, 0, 0, 0)

__device__ inline unsigned short f2bf_rne(float f) {
  unsigned u = __float_as_uint(f);
  unsigned r = u + 0x7fffu + ((u >> 16) & 1u);
  return (unsigned short)(r >> 16);
}

__device__ inline void split8(const float* s, bf16x8& hi, bf16x8& lo) {
#pragma unroll
  for (int j = 0; j < 8; ++j) {
    float f = s[j];
    unsigned short h = f2bf_rne(f);
    float fh = __uint_as_float((unsigned)h << 16);
    hi[j] = (short)h;
    lo[j] = (short)f2bf_rne(f - fh);
  }
}

__device__ inline void h8_to_f8(uint4 raw, float* out) {
  const __half2* hp = reinterpret_cast<const __half2*>(&raw);
#pragma unroll
  for (int j = 0; j < 4; ++j) {
    float2 f = __half22float2(hp[j]);
    out[2 * j] = f.x;
    out[2 * j + 1] = f.y;
  }
}

// ---------------------------------------------------------------- utilities

__global__ void zero_int_kernel(int* __restrict__ p, int n) {
  int i = blockIdx.x * blockDim.x + threadIdx.x;
  if (i < n) p[i] = 0;
}

// ----------------------------------------------- pass A: bucket histogram
__global__ __launch_bounds__(PTH) void bucket_hist(const int* __restrict__ dst,
                                                   int* __restrict__ bucket_cnt, int E) {
  __shared__ int h[NBMAX];
  int t = threadIdx.x;
  for (int i = t; i < NBMAX; i += PTH) h[i] = 0;
  __syncthreads();
  int base = blockIdx.x * PCH;
#pragma unroll
  for (int it = 0; it < PCH / PTH; ++it) {
    int e = base + it * PTH + t;
    if (e < E) {
      int d = __builtin_nontemporal_load(dst + e);
      atomicAdd(&h[d >> BSH], 1);
    }
  }
  __syncthreads();
  for (int i = t; i < NBMAX; i += PTH)
    if (h[i]) atomicAdd(&bucket_cnt[i], h[i]);
}

// ----------------------------------------------- pass S: scan bucket counts
__global__ __launch_bounds__(512) void bucket_scan(const int* __restrict__ bucket_cnt,
                                                   int* __restrict__ bucket_start,
                                                   int* __restrict__ bucket_cursor,
                                                   int* __restrict__ row_start, int N, int E) {
  __shared__ int wsum[8];
  __shared__ int wpref[8];
  int t = threadIdx.x;
  int lane = t & 63, wid = t >> 6;
  int v = bucket_cnt[t];
  int sc = v;
#pragma unroll
  for (int off = 1; off < 64; off <<= 1) {
    int u = __shfl_up(sc, off, 64);
    if (lane >= off) sc += u;
  }
  if (lane == 63) wsum[wid] = sc;
  __syncthreads();
  if (t == 0) {
    int a = 0;
#pragma unroll
    for (int w = 0; w < 8; ++w) { wpref[w] = a; a += wsum[w]; }
  }
  __syncthreads();
  int excl = wpref[wid] + sc - v;
  bucket_start[t] = excl;
  bucket_cursor[t] = excl;
  if (t == 0) row_start[N] = E;
}

// ----------------------------------------------- pass B: coalesced partition
// 1024 threads/block (16 waves) hide the LDS-atomic + global-load latency;
// grid = E/PCH = ~98 blocks, so waves-per-CU is the only parallelism lever.
__global__ __launch_bounds__(PTH) void partition_kernel(const int* __restrict__ src,
                                                        const int* __restrict__ dst,
                                                        int* bucket_cursor,
                                                        unsigned* __restrict__ packed, int E) {
  __shared__ int h[NBMAX];
  __shared__ int lofs[NBMAX];
  __shared__ int res[NBMAX];
  __shared__ int lcur[NBMAX];
  __shared__ int wsum[4];
  __shared__ int wpref[4];
  __shared__ unsigned stage[PCH];
  int t = threadIdx.x;
  int lane = t & 63;
  int base = blockIdx.x * PCH;

  for (int i = t; i < NBMAX; i += PTH) h[i] = 0;
  __syncthreads();
#pragma unroll
  for (int it = 0; it < PCH / PTH; ++it) {
    int e = base + it * PTH + t;
    if (e < E) {
      int d = __builtin_nontemporal_load(dst + e);
      atomicAdd(&h[d >> BSH], 1);
    }
  }
  __syncthreads();
  // scan 512 bins on threads 0-255 (thread t owns bins 2t, 2t+1)
  int c0 = 0, c1 = 0, s = 0, sc = 0;
  if (t < 256) {
    c0 = h[2 * t];
    c1 = h[2 * t + 1];
    s = c0 + c1;
    sc = s;
#pragma unroll
    for (int off = 1; off < 64; off <<= 1) {
      int u = __shfl_up(sc, off, 64);
      if (lane >= off) sc += u;
    }
    if (lane == 63) wsum[t >> 6] = sc;
  }
  __syncthreads();
  if (t == 0) {
    int a = 0;
#pragma unroll
    for (int w = 0; w < 4; ++w) { wpref[w] = a; a += wsum[w]; }
  }
  __syncthreads();
  if (t < 256) {
    int excl = wpref[t >> 6] + sc - s;
    lofs[2 * t] = excl;
    lofs[2 * t + 1] = excl + c0;
    lcur[2 * t] = excl;
    lcur[2 * t + 1] = excl + c0;
    if (c0 > 0) res[2 * t] = atomicAdd(&bucket_cursor[2 * t], c0);
    if (c1 > 0) res[2 * t + 1] = atomicAdd(&bucket_cursor[2 * t + 1], c1);
  }
  __syncthreads();
#pragma unroll
  for (int it = 0; it < PCH / PTH; ++it) {
    int e = base + it * PTH + t;
    if (e < E) {
      int d = __builtin_nontemporal_load(dst + e);
      int sv = __builtin_nontemporal_load(src + e);
      int pos = atomicAdd(&lcur[d >> BSH], 1);
      stage[pos] = ((unsigned)(d & ((1 << BSH) - 1)) << 16) | (unsigned)(sv & 0xffff);
    }
  }
  __syncthreads();
  // copy runs out: wave w handles buckets w, w+16, ...
  int wid = t >> 6;
  for (int b = wid; b < NBMAX; b += PTH / 64) {
    int run = h[b];
    if (run == 0) continue;
    int gbase = res[b], lbase = lofs[b];
    for (int j = lane; j < run; j += 64) packed[gbase + j] = stage[lbase + j];
  }
}

// ----------------------------------------------- pass C: per-bucket CSR build
__global__ __launch_bounds__(256) void csr_build(const unsigned* __restrict__ packed,
                                                 const int* __restrict__ bucket_start,
                                                 int* __restrict__ row_start,
                                                 float* __restrict__ inv_deg,
                                                 unsigned short* __restrict__ col, int N) {
  __shared__ int cntA[128];
  __shared__ int lcur[128];
  __shared__ int wsum2[2];
  __shared__ int wpref2[2];
  __shared__ unsigned short stage[BCAP];
  int t = threadIdx.x;
  int b = blockIdx.x;
  int s0 = bucket_start[b], s1 = bucket_start[b + 1];
  int cnt = s1 - s0;
  if (t < 128) cntA[t] = 0;
  __syncthreads();
  for (int i = t; i < cnt; i += 256) {
    unsigned p = packed[s0 + i];
    atomicAdd(&cntA[p >> 16], 1);
  }
  __syncthreads();
  if (t < 128) {
    int lane = t & 63, wid = t >> 6;
    int v = cntA[t];
    int sc = v;
#pragma unroll
    for (int off = 1; off < 64; off <<= 1) {
      int u = __shfl_up(sc, off, 64);
      if (lane >= off) sc += u;
    }
    if (lane == 63) wsum2[wid] = sc;
    __syncthreads();
    if (t == 0) { wpref2[0] = 0; wpref2[1] = wsum2[0]; }
    __syncthreads();
    int excl = wpref2[wid] + sc - v;
    lcur[t] = excl;
    int node = b * 128 + t;
    if (node < N) {
      row_start[node] = s0 + excl;
      inv_deg[node] = 1.0f / fmaxf((float)v, 1.0f);
    }
  } else {
    __syncthreads();
    __syncthreads();
  }
  __syncthreads();
  for (int i = t; i < cnt; i += 256) {
    unsigned p = packed[s0 + i];
    int pos = atomicAdd(&lcur[p >> 16], 1);
    unsigned short us = (unsigned short)(p & 0xffff);
    if (pos < BCAP) stage[pos] = us;
    else col[s0 + pos] = us;
  }
  __syncthreads();
  int lim = min(cnt, BCAP);
  for (int i = t; i < lim; i += 256) col[s0 + i] = stage[i];
}

// ------------------------------------------------ fp32 -> fp16 row convert (x)
__global__ __launch_bounds__(256) void to_f16_kernel(const float* __restrict__ in, int ld,
                                                     unsigned short* __restrict__ out, int ldo,
                                                     int nrows) {
  int idx = blockIdx.x * 256 + threadIdx.x;
  int r = idx >> 4, cc = (idx & 15) * 8;
  if (r >= nrows) return;
  const float* p = in + (size_t)r * ld + cc;
  float4 a = *reinterpret_cast<const float4*>(p);
  float4 b = *reinterpret_cast<const float4*>(p + 4);
  __half2 h0 = __floats2half2_rn(a.x, a.y);
  __half2 h1 = __floats2half2_rn(a.z, a.w);
  __half2 h2 = __floats2half2_rn(b.x, b.y);
  __half2 h3 = __floats2half2_rn(b.z, b.w);
  uint4 o;
  o.x = *reinterpret_cast<unsigned*>(&h0);
  o.y = *reinterpret_cast<unsigned*>(&h1);
  o.z = *reinterpret_cast<unsigned*>(&h2);
  o.w = *reinterpret_cast<unsigned*>(&h3);
  *reinterpret_cast<uint4*>(out + (size_t)r * ldo + cc) = o;
}

// -------------------------------------------------- weight prep (bf16 split)
__global__ __launch_bounds__(256) void prep_layer_w(const float* __restrict__ Wl,
                                                    const float* __restrict__ Wr,
                                                    bf16x8* __restrict__ f) {
  int idx = blockIdx.x * 256 + threadIdx.x;  // [0, 12288)
  int lane = idx & 63;
  int ksnt = (idx >> 6) & 31;
  int mat = (idx >> 11) & 1;
  int layer = idx >> 12;
  int ks = ksnt >> 3, nt = ksnt & 7;
  int nn = nt * 16 + (lane & 15);
  int k0 = ks * 32 + (lane >> 4) * 8;
  const float* W = (mat ? Wr : Wl) + (size_t)layer * DD * DD;
  float v[8];
#pragma unroll
  for (int j = 0; j < 8; ++j) v[j] = W[(size_t)(k0 + j) * DD + nn];
  bf16x8 hi, lo;
  split8(v, hi, lo);
  size_t base = (size_t)((layer * 2 + mat) * 2) * 2048 + (size_t)ksnt * 64 + lane;
  f[base] = hi;
  f[base + 2048] = lo;
}

__global__ __launch_bounds__(256) void prep_cls_w(const float* __restrict__ Wc1,
                                                  bf16x8* __restrict__ f) {
  int idx = blockIdx.x * 256 + threadIdx.x;  // [0, 3072)
  if (idx >= 3072) return;
  int lane = idx & 63;
  int ksnt = idx >> 6;
  int ks = ksnt >> 2, nt = ksnt & 3;
  int nn = nt * 16 + (lane & 15);
  int k0 = ks * 32 + (lane >> 4) * 8;
  float v[8];
#pragma unroll
  for (int j = 0; j < 8; ++j) v[j] = Wc1[(size_t)(k0 + j) * 64 + nn];
  bf16x8 hi, lo;
  split8(v, hi, lo);
  f[idx] = hi;
  f[idx + 3072] = lo;
}

// ------------------------------------------------------------- aggregation
__global__ __launch_bounds__(256) void agg16_kernel(const unsigned short* __restrict__ h16,
                                                    int ldh,
                                                    const int* __restrict__ row_start,
                                                    const unsigned short* __restrict__ col,
                                                    const float* __restrict__ inv_deg,
                                                    unsigned short* __restrict__ agg16, int n) {
  int wib = threadIdx.x >> 6;
  int lane = threadIdx.x & 63;
  int node = blockIdx.x * 4 + wib;
  if (node >= n) return;
  int beg = row_start[node];
  int end = row_start[node + 1];
  int q = lane >> 4, l15 = lane & 15;
  float acc[8];
#pragma unroll
  for (int k = 0; k < 8; ++k) acc[k] = 0.f;

  for (int j0 = beg; j0 < end; j0 += 64) {
    int cnt = min(64, end - j0);
    int cidx = (int)col[j0 + min(lane, cnt - 1)];
    for (int j = 0; j < cnt; j += 4) {
      int e = j + q;
      int s = __shfl(cidx, e < cnt ? e : 0);
      if (e < cnt) {
        uint4 raw = *reinterpret_cast<const uint4*>(h16 + (size_t)s * ldh + l15 * 8);
        float f8[8];
        h8_to_f8(raw, f8);
#pragma unroll
        for (int k = 0; k < 8; ++k) acc[k] += f8[k];
      }
    }
  }
#pragma unroll
  for (int m = 16; m <= 32; m <<= 1) {
#pragma unroll
    for (int k = 0; k < 8; ++k) acc[k] += __shfl_xor(acc[k], m);
  }
  if (lane < 16) {
    float w = inv_deg[node];
    __half2 h0 = __floats2half2_rn(acc[0] * w, acc[1] * w);
    __half2 h1 = __floats2half2_rn(acc[2] * w, acc[3] * w);
    __half2 h2 = __floats2half2_rn(acc[4] * w, acc[5] * w);
    __half2 h3 = __floats2half2_rn(acc[6] * w, acc[7] * w);
    uint4 o;
    o.x = *reinterpret_cast<unsigned*>(&h0);
    o.y = *reinterpret_cast<unsigned*>(&h1);
    o.z = *reinterpret_cast<unsigned*>(&h2);
    o.w = *reinterpret_cast<unsigned*>(&h3);
    *reinterpret_cast<uint4*>(agg16 + (size_t)node * DD + l15 * 8) = o;
  }
}

// ---------------------------------------- MFMA layer GEMM + BN + ReLU (no LDS)
__global__ __launch_bounds__(256) void layer_gemm_mfma(
    const float* __restrict__ hin32, const unsigned short* __restrict__ hin16, int ldh,
    const unsigned short* __restrict__ agg16,
    const bf16x8* __restrict__ Blh_g, const bf16x8* __restrict__ Bll_g,
    const bf16x8* __restrict__ Brh_g, const bf16x8* __restrict__ Brl_g,
    const float* __restrict__ bl, const float* __restrict__ gamma,
    const float* __restrict__ beta, const float* __restrict__ rmean,
    const float* __restrict__ rvar, unsigned short* __restrict__ out16, int n) {
  int t = threadIdx.x;
  int w = t >> 6, lane = t & 63;
  int lane16 = lane & 15, quad = lane >> 4;
  int row0 = blockIdx.x * 64;
  int m = row0 + w * 16 + lane16;
  bool valid = m < n;
  size_t mrow = (size_t)(valid ? m : 0);
  const unsigned short* ap = agg16 + mrow * DD + quad * 8;

  bf16x8 Ah[4], Al[4], Hh[4], Hl[4];
#pragma unroll
  for (int ks = 0; ks < 4; ++ks) {
    float a8[8], h8[8];
    if (valid) {
      uint4 raw = *reinterpret_cast<const uint4*>(ap + ks * 32);
      h8_to_f8(raw, a8);
      if (hin16) {
        uint4 rh = *reinterpret_cast<const uint4*>(hin16 + mrow * (size_t)ldh + quad * 8 + ks * 32);
        h8_to_f8(rh, h8);
      } else {
        const float* hp = hin32 + mrow * (size_t)ldh + quad * 8 + ks * 32;
        *reinterpret_cast<float4*>(h8) = *reinterpret_cast<const float4*>(hp);
        *reinterpret_cast<float4*>(h8 + 4) = *reinterpret_cast<const float4*>(hp + 4);
      }
    } else {
#pragma unroll
      for (int j = 0; j < 8; ++j) { a8[j] = 0.f; h8[j] = 0.f; }
    }
    split8(a8, Ah[ks], Al[ks]);
    split8(h8, Hh[ks], Hl[ks]);
  }

  f32x4 acc[8];
#pragma unroll
  for (int nt = 0; nt < 8; ++nt) acc[nt] = (f32x4){0.f, 0.f, 0.f, 0.f};

#pragma unroll
  for (int ks = 0; ks < 4; ++ks) {
    int fb = ks * 8 * 64 + lane;
    bf16x8 B0[8], B1[8];
#pragma unroll
    for (int nt = 0; nt < 8; ++nt) B0[nt] = Blh_g[fb + nt * 64];
#pragma unroll
    for (int nt = 0; nt < 8; ++nt) acc[nt] = MFMA(Ah[ks], B0[nt], acc[nt]);
#pragma unroll
    for (int nt = 0; nt < 8; ++nt) B1[nt] = Bll_g[fb + nt * 64];
#pragma unroll
    for (int nt = 0; nt < 8; ++nt) acc[nt] = MFMA(Al[ks], B0[nt], acc[nt]);
#pragma unroll
    for (int nt = 0; nt < 8; ++nt) acc[nt] = MFMA(Ah[ks], B1[nt], acc[nt]);
#pragma unroll
    for (int nt = 0; nt < 8; ++nt) B0[nt] = Brh_g[fb + nt * 64];
#pragma unroll
    for (int nt = 0; nt < 8; ++nt) acc[nt] = MFMA(Hh[ks], B0[nt], acc[nt]);
#pragma unroll
    for (int nt = 0; nt < 8; ++nt) B1[nt] = Brl_g[fb + nt * 64];
#pragma unroll
    for (int nt = 0; nt < 8; ++nt) acc[nt] = MFMA(Hl[ks], B0[nt], acc[nt]);
#pragma unroll
    for (int nt = 0; nt < 8; ++nt) acc[nt] = MFMA(Hh[ks], B1[nt], acc[nt]);
  }

#pragma unroll
  for (int nt = 0; nt < 8; ++nt) {
    int c = nt * 16 + lane16;
    float sc = gamma[c] * rsqrtf(rvar[c] + EPSV);
    float sh = (bl[c] - rmean[c]) * sc + beta[c];
#pragma unroll
    for (int r = 0; r < 4; ++r) {
      int orow = row0 + w * 16 + quad * 4 + r;
      if (orow < n) {
        float v = fmaxf(fmaf(acc[nt][r], sc, sh), 0.f);
        __half hv = __float2half_rn(v);
        out16[(size_t)orow * JKD + c] = *reinterpret_cast<unsigned short*>(&hv);
      }
    }
  }
}

// ------------------------------------------------------ MFMA classifier
__global__ __launch_bounds__(256) void classifier_mfma(
    const unsigned short* __restrict__ jk16, const bf16x8* __restrict__ Bh_g,
    const bf16x8* __restrict__ Bl_g, const float* __restrict__ bc1,
    const float* __restrict__ Wc2, const float* __restrict__ bc2,
    float* __restrict__ out, int n) {
  __shared__ float sZ[64][65];
  int t = threadIdx.x;
  int w = t >> 6, lane = t & 63;
  int lane16 = lane & 15, quad = lane >> 4;
  int row0 = blockIdx.x * 64;
  int m = row0 + w * 16 + lane16;
  bool valid = m < n;
  const unsigned short* jp = jk16 + (size_t)(valid ? m : 0) * JKD + quad * 8;

  f32x4 acc[4];
#pragma unroll
  for (int nt = 0; nt < 4; ++nt) acc[nt] = (f32x4){0.f, 0.f, 0.f, 0.f};

#pragma unroll
  for (int ks = 0; ks < 12; ++ks) {
    float a8[8];
    if (valid) {
      uint4 raw = *reinterpret_cast<const uint4*>(jp + ks * 32);
      h8_to_f8(raw, a8);
    } else {
#pragma unroll
      for (int j = 0; j < 8; ++j) a8[j] = 0.f;
    }
    bf16x8 Jh, Jl;
    split8(a8, Jh, Jl);
    int fb = ks * 4 * 64 + lane;
    bf16x8 B0[4], B1[4];
#pragma unroll
    for (int nt = 0; nt < 4; ++nt) B0[nt] = Bh_g[fb + nt * 64];
#pragma unroll
    for (int nt = 0; nt < 4; ++nt) acc[nt] = MFMA(Jh, B0[nt], acc[nt]);
#pragma unroll
    for (int nt = 0; nt < 4; ++nt) B1[nt] = Bl_g[fb + nt * 64];
#pragma unroll
    for (int nt = 0; nt < 4; ++nt) acc[nt] = MFMA(Jl, B0[nt], acc[nt]);
#pragma unroll
    for (int nt = 0; nt < 4; ++nt) acc[nt] = MFMA(Jh, B1[nt], acc[nt]);
  }

#pragma unroll
  for (int nt = 0; nt < 4; ++nt) {
    int c = nt * 16 + lane16;
    float b1 = bc1[c];
#pragma unroll
    for (int r = 0; r < 4; ++r)
      sZ[w * 16 + quad * 4 + r][c] = fmaxf(acc[nt][r] + b1, 0.f);
  }
  __syncthreads();

  if (t < 128) {
    int r = t >> 1, j = t & 1;
    int gr = row0 + r;
    if (gr < n) {
      float s = bc2[j];
#pragma unroll
      for (int c = 0; c < 64; ++c) s = fmaf(sZ[r][c], Wc2[c * 2 + j], s);
      out[(size_t)gr * 2 + j] = s;
    }
  }
}

// ----------------------------------------------------------------- launch

extern "C" void kernel_launch(void* const* d_in, const int* in_sizes, int n_in,
                              void* d_out, int out_size, void* d_ws, size_t ws_size,
                              hipStream_t stream) {
  const float* x = (const float*)d_in[0];
  const int* ei = (const int*)d_in[1];
  const float* Wl = (const float*)d_in[2];
  const float* bl = (const float*)d_in[3];
  const float* Wr = (const float*)d_in[4];
  const float* gamma = (const float*)d_in[5];
  const float* beta = (const float*)d_in[6];
  const float* rmean = (const float*)d_in[7];
  const float* rvar = (const float*)d_in[8];
  const float* Wc1 = (const float*)d_in[9];
  const float* bc1 = (const float*)d_in[10];
  const float* Wc2 = (const float*)d_in[11];
  const float* bc2 = (const float*)d_in[12];
  float* out = (float*)d_out;

  const int N = in_sizes[0] / DD;
  const int E = in_sizes[1] / 2;
  const int* src = ei;
  const int* dst = ei + E;

  auto align = [](size_t v) { return (v + 255) & ~(size_t)255; };
  char* ws = (char*)d_ws;
  size_t off = 0;
  int* row_start = (int*)(ws + off);  off = align(off + sizeof(int) * (size_t)(N + 1));
  unsigned short* col = (unsigned short*)(ws + off); off = align(off + sizeof(short) * (size_t)E);
  float* inv_deg = (float*)(ws + off); off = align(off + sizeof(float) * (size_t)N);
  unsigned* packed = (unsigned*)(ws + off); off = align(off + sizeof(unsigned) * (size_t)E);
  int* bucket_cnt = (int*)(ws + off);    off = align(off + sizeof(int) * NBMAX);
  int* bucket_start = (int*)(ws + off);  off = align(off + sizeof(int) * (NBMAX + 1));
  int* bucket_cursor = (int*)(ws + off); off = align(off + sizeof(int) * NBMAX);
  unsigned short* x16 = (unsigned short*)(ws + off);   off = align(off + sizeof(short) * (size_t)N * DD);
  unsigned short* agg16 = (unsigned short*)(ws + off); off = align(off + sizeof(short) * (size_t)N * DD);
  unsigned short* jk16 = (unsigned short*)(ws + off);  off = align(off + sizeof(short) * (size_t)N * JKD);
  bf16x8* wf = (bf16x8*)(ws + off);  off = align(off + (size_t)16 * 3 * 2 * 2 * 2048);
  bf16x8* wcf = (bf16x8*)(ws + off); off = align(off + (size_t)16 * 2 * 3072);

  const int nbuck = (N + 127) >> BSH;
  const int nChunks = (E + PCH - 1) / PCH;

  zero_int_kernel<<<(NBMAX + 255) / 256, 256, 0, stream>>>(bucket_cnt, NBMAX);
  bucket_hist<<<nChunks, PTH, 0, stream>>>(dst, bucket_cnt, E);
  bucket_scan<<<1, 512, 0, stream>>>(bucket_cnt, bucket_start, bucket_cursor, row_start, N, E);
  partition_kernel<<<nChunks, PTH, 0, stream>>>(src, dst, bucket_cursor, packed, E);
  csr_build<<<nbuck, 256, 0, stream>>>(packed, bucket_start, row_start, inv_deg, col, N);

  prep_layer_w<<<48, 256, 0, stream>>>(Wl, Wr, wf);
  prep_cls_w<<<12, 256, 0, stream>>>(Wc1, wcf);
  to_f16_kernel<<<(N * 16 + 255) / 256, 256, 0, stream>>>(x, DD, x16, DD, N);

  int nTiles = (N + 63) / 64;
  for (int i = 0; i < 3; ++i) {
    const unsigned short* gsrc = (i == 0) ? x16 : (jk16 + (size_t)(i - 1) * DD);
    int ldg = (i == 0) ? DD : JKD;
    agg16_kernel<<<(N + 3) / 4, 256, 0, stream>>>(gsrc, ldg, row_start, col, inv_deg, agg16, N);
    bf16x8* Wlf = wf + (size_t)(i * 2 + 0) * 2 * 2048;
    bf16x8* Wrf = wf + (size_t)(i * 2 + 1) * 2 * 2048;
    layer_gemm_mfma<<<nTiles, 256, 0, stream>>>(
        (i == 0) ? x : nullptr,
        (i == 0) ? (const unsigned short*)nullptr : (jk16 + (size_t)(i - 1) * DD),
        (i == 0) ? DD : JKD, agg16, Wlf, Wlf + 2048, Wrf, Wrf + 2048,
        bl + (size_t)i * DD, gamma + (size_t)i * DD, beta + (size_t)i * DD,
        rmean + (size_t)i * DD, rvar + (size_t)i * DD, jk16 + (size_t)i * DD, N);
  }
  classifier_mfma<<<nTiles, 256, 0, stream>>>(jk16, wcf, wcf + 3072, bc1, Wc2, bc2, out, N);
}

// Round 9
// 321.944 us; speedup vs baseline: 2.6241x; 1.0337x over previous
//
#include <hip/hip_runtime.h>
#include <hip/hip_fp16.h>
#include <cstdint>
#include <cstddef>

#define DD 128
#define JKD 384
#define EPSV 1e-5f
#define BSH 7          // bucket = dst >> 7 (128 nodes/bucket)
#define NBMAX 512      // N < 65536 (u16 col) -> <= 512 buckets
#define PCH 8192       // partition chunk (edges per block)
#define PTH 1024       // partition/hist block threads (16 waves -> latency hiding)
#define BCAP 8192      // per-bucket LDS staging capacity (pass C)

typedef __attribute__((ext_vector_type(8))) short bf16x8;
typedef __attribute__((ext_vector_type(4))) float f32x4;
#define MFMA(a, b, c) __builtin_amdgcn_mfma_f32_16x16x32_bf16(a, b, c, 0, 0, 0)

__device__ inline unsigned short f2bf_rne(float f) {
  unsigned u = __float_as_uint(f);
  unsigned r = u + 0x7fffu + ((u >> 16) & 1u);
  return (unsigned short)(r >> 16);
}

__device__ inline void split8(const float* s, bf16x8& hi, bf16x8& lo) {
#pragma unroll
  for (int j = 0; j < 8; ++j) {
    float f = s[j];
    unsigned short h = f2bf_rne(f);
    float fh = __uint_as_float((unsigned)h << 16);
    hi[j] = (short)h;
    lo[j] = (short)f2bf_rne(f - fh);
  }
}

__device__ inline void h8_to_f8(uint4 raw, float* out) {
  const __half2* hp = reinterpret_cast<const __half2*>(&raw);
#pragma unroll
  for (int j = 0; j < 4; ++j) {
    float2 f = __half22float2(hp[j]);
    out[2 * j] = f.x;
    out[2 * j + 1] = f.y;
  }
}

// ---------------------------------------------------------------- utilities

__global__ void zero_int_kernel(int* __restrict__ p, int n) {
  int i = blockIdx.x * blockDim.x + threadIdx.x;
  if (i < n) p[i] = 0;
}

// ----------------------------------------------- pass A: bucket histogram
__global__ __launch_bounds__(PTH) void bucket_hist(const int* __restrict__ dst,
                                                   int* __restrict__ bucket_cnt, int E) {
  __shared__ int h[NBMAX];
  int t = threadIdx.x;
  for (int i = t; i < NBMAX; i += PTH) h[i] = 0;
  __syncthreads();
  int base = blockIdx.x * PCH;
#pragma unroll
  for (int it = 0; it < PCH / PTH; ++it) {
    int e = base + it * PTH + t;
    if (e < E) {
      int d = __builtin_nontemporal_load(dst + e);
      atomicAdd(&h[d >> BSH], 1);
    }
  }
  __syncthreads();
  for (int i = t; i < NBMAX; i += PTH)
    if (h[i]) atomicAdd(&bucket_cnt[i], h[i]);
}

// ----------------------------------------------- pass S: scan bucket counts
__global__ __launch_bounds__(512) void bucket_scan(const int* __restrict__ bucket_cnt,
                                                   int* __restrict__ bucket_start,
                                                   int* __restrict__ bucket_cursor,
                                                   int* __restrict__ row_start, int N, int E) {
  __shared__ int wsum[8];
  __shared__ int wpref[8];
  int t = threadIdx.x;
  int lane = t & 63, wid = t >> 6;
  int v = bucket_cnt[t];
  int sc = v;
#pragma unroll
  for (int off = 1; off < 64; off <<= 1) {
    int u = __shfl_up(sc, off, 64);
    if (lane >= off) sc += u;
  }
  if (lane == 63) wsum[wid] = sc;
  __syncthreads();
  if (t == 0) {
    int a = 0;
#pragma unroll
    for (int w = 0; w < 8; ++w) { wpref[w] = a; a += wsum[w]; }
  }
  __syncthreads();
  int excl = wpref[wid] + sc - v;
  bucket_start[t] = excl;
  bucket_cursor[t] = excl;
  if (t == 0) row_start[N] = E;
}

// ----------------------------------------------- pass B: coalesced partition
__global__ __launch_bounds__(PTH) void partition_kernel(const int* __restrict__ src,
                                                        const int* __restrict__ dst,
                                                        int* bucket_cursor,
                                                        unsigned* __restrict__ packed, int E) {
  __shared__ int h[NBMAX];
  __shared__ int lofs[NBMAX];
  __shared__ int res[NBMAX];
  __shared__ int lcur[NBMAX];
  __shared__ int wsum[4];
  __shared__ int wpref[4];
  __shared__ unsigned stage[PCH];
  int t = threadIdx.x;
  int lane = t & 63;
  int base = blockIdx.x * PCH;

  for (int i = t; i < NBMAX; i += PTH) h[i] = 0;
  __syncthreads();
#pragma unroll
  for (int it = 0; it < PCH / PTH; ++it) {
    int e = base + it * PTH + t;
    if (e < E) {
      int d = __builtin_nontemporal_load(dst + e);
      atomicAdd(&h[d >> BSH], 1);
    }
  }
  __syncthreads();
  // scan 512 bins on threads 0-255 (thread t owns bins 2t, 2t+1)
  int c0 = 0, c1 = 0, s = 0, sc = 0;
  if (t < 256) {
    c0 = h[2 * t];
    c1 = h[2 * t + 1];
    s = c0 + c1;
    sc = s;
#pragma unroll
    for (int off = 1; off < 64; off <<= 1) {
      int u = __shfl_up(sc, off, 64);
      if (lane >= off) sc += u;
    }
    if (lane == 63) wsum[t >> 6] = sc;
  }
  __syncthreads();
  if (t == 0) {
    int a = 0;
#pragma unroll
    for (int w = 0; w < 4; ++w) { wpref[w] = a; a += wsum[w]; }
  }
  __syncthreads();
  if (t < 256) {
    int excl = wpref[t >> 6] + sc - s;
    lofs[2 * t] = excl;
    lofs[2 * t + 1] = excl + c0;
    lcur[2 * t] = excl;
    lcur[2 * t + 1] = excl + c0;
    if (c0 > 0) res[2 * t] = atomicAdd(&bucket_cursor[2 * t], c0);
    if (c1 > 0) res[2 * t + 1] = atomicAdd(&bucket_cursor[2 * t + 1], c1);
  }
  __syncthreads();
#pragma unroll
  for (int it = 0; it < PCH / PTH; ++it) {
    int e = base + it * PTH + t;
    if (e < E) {
      int d = __builtin_nontemporal_load(dst + e);
      int sv = __builtin_nontemporal_load(src + e);
      int pos = atomicAdd(&lcur[d >> BSH], 1);
      stage[pos] = ((unsigned)(d & ((1 << BSH) - 1)) << 16) | (unsigned)(sv & 0xffff);
    }
  }
  __syncthreads();
  int wid = t >> 6;
  for (int b = wid; b < NBMAX; b += PTH / 64) {
    int run = h[b];
    if (run == 0) continue;
    int gbase = res[b], lbase = lofs[b];
    for (int j = lane; j < run; j += 64) packed[gbase + j] = stage[lbase + j];
  }
}

// ----------------------------------------------- pass C: per-bucket CSR build
__global__ __launch_bounds__(256) void csr_build(const unsigned* __restrict__ packed,
                                                 const int* __restrict__ bucket_start,
                                                 int* __restrict__ row_start,
                                                 float* __restrict__ inv_deg,
                                                 unsigned short* __restrict__ col, int N) {
  __shared__ int cntA[128];
  __shared__ int lcur[128];
  __shared__ int wsum2[2];
  __shared__ int wpref2[2];
  __shared__ unsigned short stage[BCAP];
  int t = threadIdx.x;
  int b = blockIdx.x;
  int s0 = bucket_start[b], s1 = bucket_start[b + 1];
  int cnt = s1 - s0;
  if (t < 128) cntA[t] = 0;
  __syncthreads();
  for (int i = t; i < cnt; i += 256) {
    unsigned p = packed[s0 + i];
    atomicAdd(&cntA[p >> 16], 1);
  }
  __syncthreads();
  if (t < 128) {
    int lane = t & 63, wid = t >> 6;
    int v = cntA[t];
    int sc = v;
#pragma unroll
    for (int off = 1; off < 64; off <<= 1) {
      int u = __shfl_up(sc, off, 64);
      if (lane >= off) sc += u;
    }
    if (lane == 63) wsum2[wid] = sc;
    __syncthreads();
    if (t == 0) { wpref2[0] = 0; wpref2[1] = wsum2[0]; }
    __syncthreads();
    int excl = wpref2[wid] + sc - v;
    lcur[t] = excl;
    int node = b * 128 + t;
    if (node < N) {
      row_start[node] = s0 + excl;
      inv_deg[node] = 1.0f / fmaxf((float)v, 1.0f);
    }
  } else {
    __syncthreads();
    __syncthreads();
  }
  __syncthreads();
  for (int i = t; i < cnt; i += 256) {
    unsigned p = packed[s0 + i];
    int pos = atomicAdd(&lcur[p >> 16], 1);
    unsigned short us = (unsigned short)(p & 0xffff);
    if (pos < BCAP) stage[pos] = us;
    else col[s0 + pos] = us;
  }
  __syncthreads();
  int lim = min(cnt, BCAP);
  for (int i = t; i < lim; i += 256) col[s0 + i] = stage[i];
}

// ------------------------------------------------ fp32 -> fp16 row convert (x)
__global__ __launch_bounds__(256) void to_f16_kernel(const float* __restrict__ in, int ld,
                                                     unsigned short* __restrict__ out, int ldo,
                                                     int nrows) {
  int idx = blockIdx.x * 256 + threadIdx.x;
  int r = idx >> 4, cc = (idx & 15) * 8;
  if (r >= nrows) return;
  const float* p = in + (size_t)r * ld + cc;
  float4 a = *reinterpret_cast<const float4*>(p);
  float4 b = *reinterpret_cast<const float4*>(p + 4);
  __half2 h0 = __floats2half2_rn(a.x, a.y);
  __half2 h1 = __floats2half2_rn(a.z, a.w);
  __half2 h2 = __floats2half2_rn(b.x, b.y);
  __half2 h3 = __floats2half2_rn(b.z, b.w);
  uint4 o;
  o.x = *reinterpret_cast<unsigned*>(&h0);
  o.y = *reinterpret_cast<unsigned*>(&h1);
  o.z = *reinterpret_cast<unsigned*>(&h2);
  o.w = *reinterpret_cast<unsigned*>(&h3);
  *reinterpret_cast<uint4*>(out + (size_t)r * ldo + cc) = o;
}

// -------------------------------------------------- weight prep (bf16 split)
__global__ __launch_bounds__(256) void prep_layer_w(const float* __restrict__ Wl,
                                                    const float* __restrict__ Wr,
                                                    bf16x8* __restrict__ f) {
  int idx = blockIdx.x * 256 + threadIdx.x;  // [0, 12288)
  int lane = idx & 63;
  int ksnt = (idx >> 6) & 31;
  int mat = (idx >> 11) & 1;
  int layer = idx >> 12;
  int ks = ksnt >> 3, nt = ksnt & 7;
  int nn = nt * 16 + (lane & 15);
  int k0 = ks * 32 + (lane >> 4) * 8;
  const float* W = (mat ? Wr : Wl) + (size_t)layer * DD * DD;
  float v[8];
#pragma unroll
  for (int j = 0; j < 8; ++j) v[j] = W[(size_t)(k0 + j) * DD + nn];
  bf16x8 hi, lo;
  split8(v, hi, lo);
  size_t base = (size_t)((layer * 2 + mat) * 2) * 2048 + (size_t)ksnt * 64 + lane;
  f[base] = hi;
  f[base + 2048] = lo;
}

__global__ __launch_bounds__(256) void prep_cls_w(const float* __restrict__ Wc1,
                                                  bf16x8* __restrict__ f) {
  int idx = blockIdx.x * 256 + threadIdx.x;  // [0, 3072)
  if (idx >= 3072) return;
  int lane = idx & 63;
  int ksnt = idx >> 6;
  int ks = ksnt >> 2, nt = ksnt & 3;
  int nn = nt * 16 + (lane & 15);
  int k0 = ks * 32 + (lane >> 4) * 8;
  float v[8];
#pragma unroll
  for (int j = 0; j < 8; ++j) v[j] = Wc1[(size_t)(k0 + j) * 64 + nn];
  bf16x8 hi, lo;
  split8(v, hi, lo);
  f[idx] = hi;
  f[idx + 3072] = lo;
}

// ------------------------------------------------------------- aggregation
// 16 edges in flight per wave (4 rows per quad loaded into raw[4] before any
// accumulate) -> ONE vmcnt wait per typical node (deg~16) instead of four.
__global__ __launch_bounds__(256) void agg16_kernel(const unsigned short* __restrict__ h16,
                                                    int ldh,
                                                    const int* __restrict__ row_start,
                                                    const unsigned short* __restrict__ col,
                                                    const float* __restrict__ inv_deg,
                                                    unsigned short* __restrict__ agg16, int n) {
  int wib = threadIdx.x >> 6;
  int lane = threadIdx.x & 63;
  int node = blockIdx.x * 4 + wib;
  if (node >= n) return;
  int beg = row_start[node];
  int end = row_start[node + 1];
  int q = lane >> 4, l15 = lane & 15;
  float acc[8];
#pragma unroll
  for (int k = 0; k < 8; ++k) acc[k] = 0.f;

  for (int j0 = beg; j0 < end; j0 += 16) {
    int cnt = end - j0;
    if (cnt > 16) cnt = 16;
    int cidx = (int)col[j0 + min(l15, cnt - 1)];
    uint4 raw[4];
    bool val[4];
#pragma unroll
    for (int k = 0; k < 4; ++k) {
      int e = k * 4 + q;
      int s = __shfl(cidx, e < cnt ? e : 0);
      val[k] = e < cnt;
      if (val[k]) raw[k] = *reinterpret_cast<const uint4*>(h16 + (size_t)s * ldh + l15 * 8);
    }
#pragma unroll
    for (int k = 0; k < 4; ++k) {
      if (val[k]) {
        float f8[8];
        h8_to_f8(raw[k], f8);
#pragma unroll
        for (int c = 0; c < 8; ++c) acc[c] += f8[c];
      }
    }
  }
#pragma unroll
  for (int m = 16; m <= 32; m <<= 1) {
#pragma unroll
    for (int k = 0; k < 8; ++k) acc[k] += __shfl_xor(acc[k], m);
  }
  if (lane < 16) {
    float w = inv_deg[node];
    __half2 h0 = __floats2half2_rn(acc[0] * w, acc[1] * w);
    __half2 h1 = __floats2half2_rn(acc[2] * w, acc[3] * w);
    __half2 h2 = __floats2half2_rn(acc[4] * w, acc[5] * w);
    __half2 h3 = __floats2half2_rn(acc[6] * w, acc[7] * w);
    uint4 o;
    o.x = *reinterpret_cast<unsigned*>(&h0);
    o.y = *reinterpret_cast<unsigned*>(&h1);
    o.z = *reinterpret_cast<unsigned*>(&h2);
    o.w = *reinterpret_cast<unsigned*>(&h3);
    *reinterpret_cast<uint4*>(agg16 + (size_t)node * DD + l15 * 8) = o;
  }
}

// ---------------------------------------- MFMA layer GEMM + BN + ReLU (no LDS)
// All activations fp16: A = agg16, H = x16 (layer 0) or jk16 prev slice.
__global__ __launch_bounds__(256) void layer_gemm_mfma(
    const unsigned short* __restrict__ hin16, int ldh,
    const unsigned short* __restrict__ agg16,
    const bf16x8* __restrict__ Blh_g, const bf16x8* __restrict__ Bll_g,
    const bf16x8* __restrict__ Brh_g, const bf16x8* __restrict__ Brl_g,
    const float* __restrict__ bl, const float* __restrict__ gamma,
    const float* __restrict__ beta, const float* __restrict__ rmean,
    const float* __restrict__ rvar, unsigned short* __restrict__ out16, int n) {
  int t = threadIdx.x;
  int w = t >> 6, lane = t & 63;
  int lane16 = lane & 15, quad = lane >> 4;
  int row0 = blockIdx.x * 64;
  int m = row0 + w * 16 + lane16;
  bool valid = m < n;
  size_t mrow = (size_t)(valid ? m : 0);
  const unsigned short* ap = agg16 + mrow * DD + quad * 8;
  const unsigned short* hp = hin16 + mrow * (size_t)ldh + quad * 8;

  bf16x8 Ah[4], Al[4], Hh[4], Hl[4];
#pragma unroll
  for (int ks = 0; ks < 4; ++ks) {
    float a8[8], h8[8];
    if (valid) {
      uint4 ra = *reinterpret_cast<const uint4*>(ap + ks * 32);
      uint4 rh = *reinterpret_cast<const uint4*>(hp + ks * 32);
      h8_to_f8(ra, a8);
      h8_to_f8(rh, h8);
    } else {
#pragma unroll
      for (int j = 0; j < 8; ++j) { a8[j] = 0.f; h8[j] = 0.f; }
    }
    split8(a8, Ah[ks], Al[ks]);
    split8(h8, Hh[ks], Hl[ks]);
  }

  f32x4 acc[8];
#pragma unroll
  for (int nt = 0; nt < 8; ++nt) acc[nt] = (f32x4){0.f, 0.f, 0.f, 0.f};

#pragma unroll
  for (int ks = 0; ks < 4; ++ks) {
    int fb = ks * 8 * 64 + lane;
    bf16x8 B0[8], B1[8];
#pragma unroll
    for (int nt = 0; nt < 8; ++nt) B0[nt] = Blh_g[fb + nt * 64];
#pragma unroll
    for (int nt = 0; nt < 8; ++nt) acc[nt] = MFMA(Ah[ks], B0[nt], acc[nt]);
#pragma unroll
    for (int nt = 0; nt < 8; ++nt) B1[nt] = Bll_g[fb + nt * 64];
#pragma unroll
    for (int nt = 0; nt < 8; ++nt) acc[nt] = MFMA(Al[ks], B0[nt], acc[nt]);
#pragma unroll
    for (int nt = 0; nt < 8; ++nt) acc[nt] = MFMA(Ah[ks], B1[nt], acc[nt]);
#pragma unroll
    for (int nt = 0; nt < 8; ++nt) B0[nt] = Brh_g[fb + nt * 64];
#pragma unroll
    for (int nt = 0; nt < 8; ++nt) acc[nt] = MFMA(Hh[ks], B0[nt], acc[nt]);
#pragma unroll
    for (int nt = 0; nt < 8; ++nt) B1[nt] = Brl_g[fb + nt * 64];
#pragma unroll
    for (int nt = 0; nt < 8; ++nt) acc[nt] = MFMA(Hl[ks], B0[nt], acc[nt]);
#pragma unroll
    for (int nt = 0; nt < 8; ++nt) acc[nt] = MFMA(Hh[ks], B1[nt], acc[nt]);
  }

#pragma unroll
  for (int nt = 0; nt < 8; ++nt) {
    int c = nt * 16 + lane16;
    float sc = gamma[c] * rsqrtf(rvar[c] + EPSV);
    float sh = (bl[c] - rmean[c]) * sc + beta[c];
#pragma unroll
    for (int r = 0; r < 4; ++r) {
      int orow = row0 + w * 16 + quad * 4 + r;
      if (orow < n) {
        float v = fmaxf(fmaf(acc[nt][r], sc, sh), 0.f);
        __half hv = __float2half_rn(v);
        out16[(size_t)orow * JKD + c] = *reinterpret_cast<unsigned short*>(&hv);
      }
    }
  }
}

// ------------------------------------------------------ MFMA classifier
__global__ __launch_bounds__(256) void classifier_mfma(
    const unsigned short* __restrict__ jk16, const bf16x8* __restrict__ Bh_g,
    const bf16x8* __restrict__ Bl_g, const float* __restrict__ bc1,
    const float* __restrict__ Wc2, const float* __restrict__ bc2,
    float* __restrict__ out, int n) {
  __shared__ float sZ[64][65];
  int t = threadIdx.x;
  int w = t >> 6, lane = t & 63;
  int lane16 = lane & 15, quad = lane >> 4;
  int row0 = blockIdx.x * 64;
  int m = row0 + w * 16 + lane16;
  bool valid = m < n;
  const unsigned short* jp = jk16 + (size_t)(valid ? m : 0) * JKD + quad * 8;

  f32x4 acc[4];
#pragma unroll
  for (int nt = 0; nt < 4; ++nt) acc[nt] = (f32x4){0.f, 0.f, 0.f, 0.f};

#pragma unroll
  for (int ks = 0; ks < 12; ++ks) {
    float a8[8];
    if (valid) {
      uint4 raw = *reinterpret_cast<const uint4*>(jp + ks * 32);
      h8_to_f8(raw, a8);
    } else {
#pragma unroll
      for (int j = 0; j < 8; ++j) a8[j] = 0.f;
    }
    bf16x8 Jh, Jl;
    split8(a8, Jh, Jl);
    int fb = ks * 4 * 64 + lane;
    bf16x8 B0[4], B1[4];
#pragma unroll
    for (int nt = 0; nt < 4; ++nt) B0[nt] = Bh_g[fb + nt * 64];
#pragma unroll
    for (int nt = 0; nt < 4; ++nt) acc[nt] = MFMA(Jh, B0[nt], acc[nt]);
#pragma unroll
    for (int nt = 0; nt < 4; ++nt) B1[nt] = Bl_g[fb + nt * 64];
#pragma unroll
    for (int nt = 0; nt < 4; ++nt) acc[nt] = MFMA(Jl, B0[nt], acc[nt]);
#pragma unroll
    for (int nt = 0; nt < 4; ++nt) acc[nt] = MFMA(Jh, B1[nt], acc[nt]);
  }

#pragma unroll
  for (int nt = 0; nt < 4; ++nt) {
    int c = nt * 16 + lane16;
    float b1 = bc1[c];
#pragma unroll
    for (int r = 0; r < 4; ++r)
      sZ[w * 16 + quad * 4 + r][c] = fmaxf(acc[nt][r] + b1, 0.f);
  }
  __syncthreads();

  if (t < 128) {
    int r = t >> 1, j = t & 1;
    int gr = row0 + r;
    if (gr < n) {
      float s = bc2[j];
#pragma unroll
      for (int c = 0; c < 64; ++c) s = fmaf(sZ[r][c], Wc2[c * 2 + j], s);
      out[(size_t)gr * 2 + j] = s;
    }
  }
}

// ----------------------------------------------------------------- launch

extern "C" void kernel_launch(void* const* d_in, const int* in_sizes, int n_in,
                              void* d_out, int out_size, void* d_ws, size_t ws_size,
                              hipStream_t stream) {
  const float* x = (const float*)d_in[0];
  const int* ei = (const int*)d_in[1];
  const float* Wl = (const float*)d_in[2];
  const float* bl = (const float*)d_in[3];
  const float* Wr = (const float*)d_in[4];
  const float* gamma = (const float*)d_in[5];
  const float* beta = (const float*)d_in[6];
  const float* rmean = (const float*)d_in[7];
  const float* rvar = (const float*)d_in[8];
  const float* Wc1 = (const float*)d_in[9];
  const float* bc1 = (const float*)d_in[10];
  const float* Wc2 = (const float*)d_in[11];
  const float* bc2 = (const float*)d_in[12];
  float* out = (float*)d_out;

  const int N = in_sizes[0] / DD;
  const int E = in_sizes[1] / 2;
  const int* src = ei;
  const int* dst = ei + E;

  auto align = [](size_t v) { return (v + 255) & ~(size_t)255; };
  char* ws = (char*)d_ws;
  size_t off = 0;
  int* row_start = (int*)(ws + off);  off = align(off + sizeof(int) * (size_t)(N + 1));
  unsigned short* col = (unsigned short*)(ws + off); off = align(off + sizeof(short) * (size_t)E);
  float* inv_deg = (float*)(ws + off); off = align(off + sizeof(float) * (size_t)N);
  unsigned* packed = (unsigned*)(ws + off); off = align(off + sizeof(unsigned) * (size_t)E);
  int* bucket_cnt = (int*)(ws + off);    off = align(off + sizeof(int) * NBMAX);
  int* bucket_start = (int*)(ws + off);  off = align(off + sizeof(int) * (NBMAX + 1));
  int* bucket_cursor = (int*)(ws + off); off = align(off + sizeof(int) * NBMAX);
  unsigned short* x16 = (unsigned short*)(ws + off);   off = align(off + sizeof(short) * (size_t)N * DD);
  unsigned short* agg16 = (unsigned short*)(ws + off); off = align(off + sizeof(short) * (size_t)N * DD);
  unsigned short* jk16 = (unsigned short*)(ws + off);  off = align(off + sizeof(short) * (size_t)N * JKD);
  bf16x8* wf = (bf16x8*)(ws + off);  off = align(off + (size_t)16 * 3 * 2 * 2 * 2048);
  bf16x8* wcf = (bf16x8*)(ws + off); off = align(off + (size_t)16 * 2 * 3072);

  const int nbuck = (N + 127) >> BSH;
  const int nChunks = (E + PCH - 1) / PCH;

  zero_int_kernel<<<(NBMAX + 255) / 256, 256, 0, stream>>>(bucket_cnt, NBMAX);
  bucket_hist<<<nChunks, PTH, 0, stream>>>(dst, bucket_cnt, E);
  bucket_scan<<<1, 512, 0, stream>>>(bucket_cnt, bucket_start, bucket_cursor, row_start, N, E);
  partition_kernel<<<nChunks, PTH, 0, stream>>>(src, dst, bucket_cursor, packed, E);
  csr_build<<<nbuck, 256, 0, stream>>>(packed, bucket_start, row_start, inv_deg, col, N);

  prep_layer_w<<<48, 256, 0, stream>>>(Wl, Wr, wf);
  prep_cls_w<<<12, 256, 0, stream>>>(Wc1, wcf);
  to_f16_kernel<<<(N * 16 + 255) / 256, 256, 0, stream>>>(x, DD, x16, DD, N);

  int nTiles = (N + 63) / 64;
  for (int i = 0; i < 3; ++i) {
    const unsigned short* gsrc = (i == 0) ? x16 : (jk16 + (size_t)(i - 1) * DD);
    int ldg = (i == 0) ? DD : JKD;
    agg16_kernel<<<(N + 3) / 4, 256, 0, stream>>>(gsrc, ldg, row_start, col, inv_deg, agg16, N);
    bf16x8* Wlf = wf + (size_t)(i * 2 + 0) * 2 * 2048;
    bf16x8* Wrf = wf + (size_t)(i * 2 + 1) * 2 * 2048;
    layer_gemm_mfma<<<nTiles, 256, 0, stream>>>(
        gsrc, ldg, agg16, Wlf, Wlf + 2048, Wrf, Wrf + 2048,
        bl + (size_t)i * DD, gamma + (size_t)i * DD, beta + (size_t)i * DD,
        rmean + (size_t)i * DD, rvar + (size_t)i * DD, jk16 + (size_t)i * DD, N);
  }
  classifier_mfma<<<nTiles, 256, 0, stream>>>(jk16, wcf, wcf + 3072, bc1, Wc2, bc2, out, N);
}